// Round 7
// baseline (6449.784 us; speedup 1.0000x reference)
//
#include <hip/hip_runtime.h>
#include <math.h>

#define NROWS 2048
#define KNEI  8
#define LSEQ  64
#define HD    512
#define HD4   128
#define HDP2  520
#define LATD  128
#define NHPN  4
#define NNUC  5

typedef __attribute__((ext_vector_type(8))) short s8b;   // 8 bf16 (16B)
typedef __attribute__((ext_vector_type(4))) float f4;    // MFMA acc

#define MFMA16(a,b,c) __builtin_amdgcn_mfma_f32_16x16x32_bf16(a,b,c,0,0,0)

__device__ __forceinline__ f4 f4zero(){ f4 z; z[0]=0.f; z[1]=0.f; z[2]=0.f; z[3]=0.f; return z; }
__device__ __forceinline__ float sigf(float x){ return __fdividef(1.0f, 1.0f + __expf(-x)); }
__device__ __forceinline__ float tanhf_fast(float x){
  float e = __expf(-2.0f*fabsf(x));
  float t = __fdividef(1.0f - e, 1.0f + e);
  return x >= 0.f ? t : -t;
}
__device__ __forceinline__ unsigned short f2bf(float x){
  union{float f; unsigned u;} v; v.f = x;
  unsigned r = (v.u + 0x7FFFu + ((v.u>>16)&1u)) >> 16;
  return (unsigned short)r;
}
__device__ __forceinline__ float bf2f(unsigned short u){
  union{unsigned x; float f;} v; v.x = ((unsigned)u)<<16; return v.f;
}
__device__ __forceinline__ float bflo(unsigned u){ union{unsigned x; float f;} v; v.x = u<<16; return v.f; }
__device__ __forceinline__ float bfhi(unsigned u){ union{unsigned x; float f;} v; v.x = u & 0xFFFF0000u; return v.f; }

// ----- fp32 helpers for graphgru -----
__device__ __forceinline__ void fma4(float4& a, float s, float4 w){
  a.x = fmaf(s,w.x,a.x); a.y = fmaf(s,w.y,a.y); a.z = fmaf(s,w.z,a.z); a.w = fmaf(s,w.w,a.w);
}
__device__ __forceinline__ void add4(float4& a, float4 b){ a.x+=b.x; a.y+=b.y; a.z+=b.z; a.w+=b.w; }
__device__ __forceinline__ float4 sig4(float4 v){
  return make_float4(1.f/(1.f+__expf(-v.x)),1.f/(1.f+__expf(-v.y)),1.f/(1.f+__expf(-v.z)),1.f/(1.f+__expf(-v.w)));
}
__device__ __forceinline__ float4 relu4(float4 v){ return make_float4(fmaxf(v.x,0.f),fmaxf(v.y,0.f),fmaxf(v.z,0.f),fmaxf(v.w,0.f)); }
__device__ __forceinline__ float dot4(float4 a, float4 b){ return a.x*b.x + a.y*b.y + a.z*b.z + a.w*b.w; }
__device__ __forceinline__ float4 gate_mul(float4 tv, float4 e){
  return make_float4((1.f/(1.f+__expf(-tv.x)))*e.x,(1.f/(1.f+__expf(-tv.y)))*e.y,
                     (1.f/(1.f+__expf(-tv.z)))*e.z,(1.f/(1.f+__expf(-tv.w)))*e.w);
}
__device__ __forceinline__ float4 gru_out(float4 z, float4 hprev, float4 pre){
  return make_float4((1.f-z.x)*hprev.x + z.x*tanhf(pre.x),
                     (1.f-z.y)*hprev.y + z.y*tanhf(pre.y),
                     (1.f-z.z)*hprev.z + z.z*tanhf(pre.z),
                     (1.f-z.w)*hprev.w + z.w*tanhf(pre.w));
}

// ---------------- prep kernels ----------------

__global__ void transpose_w(const float* __restrict__ src, float* __restrict__ dst,
                            int src_cols, int col_off, int nh){
  int idx = blockIdx.x*256 + threadIdx.x;
  if (idx >= nh*HD) return;
  int h = idx / HD, o = idx - h*HD;
  dst[idx] = src[o*src_cols + col_off + h];
}

// B-frag layout (per 16x16x32 tile, 1KB): dst[tile*512 + l*8 + j] = W[n][k]
// tile = ot*16+kc ; n = ot*16+(l&15) ; k = kc*32+(l>>4)*8+j
__global__ void fragprep_k(const float* __restrict__ W, short* __restrict__ dst,
                           int src_cols, int col_off){
  int idx = blockIdx.x*256 + threadIdx.x;
  if (idx >= HD*HD) return;
  int j = idx&7, l = (idx>>3)&63, tile = idx>>9;
  int kc = tile&15, ot = tile>>4;
  int row = ot*16 + (l&15), k = kc*32 + (l>>4)*8 + j;
  dst[idx] = (short)f2bf(W[(size_t)row*src_cols + col_off + k]);
}

// wxb[c*HD + n] = W[n][c] + b[n]
__global__ void wxbprep_k(const float* __restrict__ W, const float* __restrict__ b,
                          float* __restrict__ dst, int src_cols){
  int idx = blockIdx.x*256 + threadIdx.x;
  if (idx >= NNUC*HD) return;
  int c = idx/HD, n = idx - c*HD;
  dst[idx] = W[(size_t)n*src_cols + c] + b[n];
}

// latp[n][o] = b_nl[o] + sum_q gl[n][q]*wtlat[q*HD+o]
__global__ __launch_bounds__(512) void latp_k(const float* __restrict__ gl, const float* __restrict__ wtlat,
                     const float* __restrict__ bnl, float* __restrict__ latp){
  __shared__ float gls[16][LATD];
  int b = blockIdx.x, t = threadIdx.x;
  for (int i=t;i<16*LATD;i+=512) gls[i/LATD][i%LATD] = gl[(size_t)(b*16)*LATD + i];
  __syncthreads();
  float acc[16];
  float bv = bnl[t];
  #pragma unroll
  for (int r=0;r<16;++r) acc[r]=bv;
  for (int q=0;q<LATD;++q){
    float wv = wtlat[(size_t)q*HD + t];
    #pragma unroll
    for (int r=0;r<16;++r) acc[r] = fmaf(gls[r][q], wv, acc[r]);
  }
  #pragma unroll
  for (int r=0;r<16;++r) latp[(size_t)(b*16+r)*HD + t] = acc[r];
}

// ---------------- GraphGRU (unchanged fp32 path) ----------------
__global__ __launch_bounds__(512) void graphgru_k(
    const int* __restrict__ hpn_idx, const float* __restrict__ h_nei,
    const float* __restrict__ wt_z, const float* __restrict__ wx_z, const float* __restrict__ bz,
    const float* __restrict__ wx_r, const float* __restrict__ br,
    const float* __restrict__ wt_ur,
    const float* __restrict__ wt_h, const float* __restrict__ wx_h, const float* __restrict__ bh,
    const float* __restrict__ wt_topo, const float* __restrict__ b_topo_nl,
    const float* __restrict__ w_topo, const float* __restrict__ b_topo,
    float* __restrict__ msg, float* __restrict__ out_stop)
{
  __shared__ float sumh[8][HD];
  __shared__ float hk[8][HD];
  __shared__ float sg[8][HD];
  __shared__ float red[8][2];
  const int t = threadIdx.x, lane = t&63, wv = t>>6;
  const int r0 = (wv>>1)<<1;
  const int oh = wv&1;
  const int ob4 = 64*oh + lane;
  const int n0 = blockIdx.x*8;
  float4* sumh4 = (float4*)(&sumh[0][0]);
  float4* hk4   = (float4*)(&hk[0][0]);
  float4* sg4   = (float4*)(&sg[0][0]);
  const float4* hn4 = (const float4*)h_nei;

  for (int idx=t; idx<8*HD4; idx+=512){
    int r = idx>>7, c = idx&127;
    size_t base = ((size_t)(n0+r))*KNEI*HD4 + c;
    float4 s = hn4[base];
    #pragma unroll
    for (int k=1;k<KNEI;++k) add4(s, hn4[base + (size_t)k*HD4]);
    sumh4[idx] = s;
  }
  __syncthreads();

  const int hp0 = hpn_idx[n0+r0], hp1 = hpn_idx[n0+r0+1];
  const float4* bz4 = (const float4*)bz;
  const float4* wxz4 = (const float4*)wx_z;
  const float4* wtz4 = (const float4*)wt_z;
  float4 z0 = bz4[ob4]; add4(z0, wxz4[hp0*HD4 + ob4]);
  float4 z1 = bz4[ob4]; add4(z1, wxz4[hp1*HD4 + ob4]);
  for (int h=0;h<HD;++h){
    float a0 = sumh[r0][h], a1 = sumh[r0+1][h];
    float4 w = wtz4[h*HD4 + ob4];
    fma4(z0,a0,w); fma4(z1,a1,w);
  }
  z0 = sig4(z0); z1 = sig4(z1);

  const float4* br4 = (const float4*)br;
  const float4* wxr4 = (const float4*)wx_r;
  const float4* wtur4 = (const float4*)wt_ur;
  float4 rb0 = br4[ob4]; add4(rb0, wxr4[hp0*HD4 + ob4]);
  float4 rb1 = br4[ob4]; add4(rb1, wxr4[hp1*HD4 + ob4]);
  float4 sg0 = make_float4(0.f,0.f,0.f,0.f), sg1 = sg0;
  for (int k=0;k<KNEI;++k){
    __syncthreads();
    for (int idx=t; idx<8*HD4; idx+=512){
      int r = idx>>7, c = idx&127;
      hk4[idx] = hn4[((size_t)(n0+r)*KNEI + (size_t)k)*HD4 + c];
    }
    __syncthreads();
    float4 t0 = rb0, t1 = rb1;
    for (int h=0;h<HD;++h){
      float a0 = hk[r0][h], a1 = hk[r0+1][h];
      float4 w = wtur4[h*HD4 + ob4];
      fma4(t0,a0,w); fma4(t1,a1,w);
    }
    float4 e0 = hk4[r0*HD4 + ob4], e1 = hk4[(r0+1)*HD4 + ob4];
    add4(sg0, gate_mul(t0, e0));
    add4(sg1, gate_mul(t1, e1));
  }
  __syncthreads();
  sg4[r0*HD4+ob4] = sg0; sg4[(r0+1)*HD4+ob4] = sg1;
  __syncthreads();

  const float4* bh4 = (const float4*)bh;
  const float4* wxh4 = (const float4*)wx_h;
  const float4* wth4 = (const float4*)wt_h;
  float4 p0 = bh4[ob4]; add4(p0, wxh4[hp0*HD4+ob4]);
  float4 p1 = bh4[ob4]; add4(p1, wxh4[hp1*HD4+ob4]);
  for (int h=0;h<HD;++h){
    float a0 = sg[r0][h], a1 = sg[r0+1][h];
    float4 w = wth4[h*HD4+ob4];
    fma4(p0,a0,w); fma4(p1,a1,w);
  }
  float4 sh0 = sumh4[r0*HD4+ob4], sh1 = sumh4[(r0+1)*HD4+ob4];
  float4 m0 = gru_out(z0, sh0, p0);
  float4 m1 = gru_out(z1, sh1, p1);
  ((float4*)msg)[(size_t)(n0+r0)*HD4 + ob4] = m0;
  ((float4*)msg)[(size_t)(n0+r0+1)*HD4 + ob4] = m1;
  __syncthreads();
  sg4[r0*HD4+ob4] = m0; sg4[(r0+1)*HD4+ob4] = m1;
  __syncthreads();

  const float4* btnl4 = (const float4*)b_topo_nl;
  const float4* wttopo4 = (const float4*)wt_topo;
  float4 q0 = btnl4[ob4], q1 = btnl4[ob4];
  for (int h=0;h<HD;++h){
    float a0 = sg[r0][h], a1 = sg[r0+1][h];
    float4 w = wttopo4[h*HD4+ob4];
    fma4(q0,a0,w); fma4(q1,a1,w);
  }
  float4 wt4v = ((const float4*)w_topo)[ob4];
  float th0 = dot4(relu4(q0), wt4v);
  float th1 = dot4(relu4(q1), wt4v);
  #pragma unroll
  for (int s=32;s>0;s>>=1){ th0 += __shfl_down(th0,s); th1 += __shfl_down(th1,s); }
  if (lane==0){ red[r0][oh]=th0; red[r0+1][oh]=th1; }
  __syncthreads();
  if (t<8) out_stop[n0+t] = red[t][0] + red[t][1] + b_topo[0];
}

// ---------------- MFMA scan: register-pipelined weight streaming ----------------
// 64 blocks x 512 threads (8 waves), 32 rows/block, all 64 steps.
// A = h-frag (LDS), B = weight frag, two-set rotation depth-2 prefetch.
// __launch_bounds__(512,1): 256-VGPR budget so the prefetch sets actually
// stay in registers (round 6's 128 cap silently serialized the pipeline).
// D: row = mt*16 + g*4 + q (GRU row), col = (4w+i)*16 + lm (hidden unit).

__global__ __launch_bounds__(512, 1) void scan_pipe_k(
    const int* __restrict__ nuc_idx,
    const float* __restrict__ msg,
    const short* __restrict__ fz, const short* __restrict__ fr,
    const short* __restrict__ fh, const short* __restrict__ fnuc,
    const short* __restrict__ fhpn,
    const float* __restrict__ wxbz, const float* __restrict__ wxbr, const float* __restrict__ wxbh,
    const float* __restrict__ latp,
    const float* __restrict__ w_nuc, const float* __restrict__ b_nuc,
    const float* __restrict__ b_hpn_nl, const float* __restrict__ w_hpn, const float* __restrict__ b_hpn,
    float* __restrict__ out_newh, float* __restrict__ out_hpn, float* __restrict__ out_nuc)
{
  __shared__ __align__(16) short buf0[32][HDP2];       // bf16 h       (33.3KB)
  __shared__ __align__(16) short buf1[32][HDP2];       // bf16 gated-h (33.3KB)
  __shared__ unsigned short wxb_s[3][NNUC][HDP2];      // bf16 bias tables
  __shared__ unsigned short wns_s[NNUC][HD];           // bf16 nuc-out weights
  __shared__ float redbuf[8][32][6];
  __shared__ int   codes_s[32];

  const int t = threadIdx.x, l = t&63, w = t>>6;
  const int lm = l&15, g = l>>4;
  const int n0 = blockIdx.x*32;

  for (int i=t;i<3*NNUC*HD;i+=512){
    int tb=i/(NNUC*HD), r2=i-tb*(NNUC*HD);
    const float* src = (tb==0)?wxbz:((tb==1)?wxbr:wxbh);
    wxb_s[tb][r2/HD][r2%HD] = f2bf(src[r2]);
  }
  for (int i=t;i<NNUC*HD;i+=512) wns_s[i/HD][i&511] = f2bf(w_nuc[i]);
  for (int i=t;i<32*HD;i+=512){
    int r2=i>>9, c=i&511;
    buf0[r2][c] = (short)f2bf(msg[(size_t)(n0+r2)*HD + c]);
  }
  if (t<32) codes_s[t] = nuc_idx[(size_t)(n0+t)*LSEQ];
  float bn = 0.f;
  if (t<160) bn = b_nuc[t - (t/5)*5];

  // fp32 h master + packed bf16 lat_part at this lane's D coords
  float hO[4][2][4];
  unsigned lpk[4][2][2];
  #pragma unroll
  for (int i=0;i<4;++i){
    int col=(4*w+i)*16+lm;
    #pragma unroll
    for (int mt=0;mt<2;++mt){
      float lv[4];
      #pragma unroll
      for (int q=0;q<4;++q){
        size_t idx = (size_t)(n0+mt*16+g*4+q)*HD + col;
        hO[i][mt][q] = msg[idx];
        lv[q] = latp[idx];
      }
      lpk[i][mt][0] = (unsigned)f2bf(lv[0]) | ((unsigned)f2bf(lv[1])<<16);
      lpk[i][mt][1] = (unsigned)f2bf(lv[2]) | ((unsigned)f2bf(lv[3])<<16);
    }
  }
  __syncthreads();

  const s8b* BZ = (const s8b*)fz;
  const s8b* BR = (const s8b*)fr;
  const s8b* BH = (const s8b*)fh;
  const s8b* BN = (const s8b*)fnuc;
  int tbase[4];
  #pragma unroll
  for (int i=0;i<4;++i) tbase[i] = ((4*w+i)*16)*64 + l;

  f4 za[4][2], ra[4][2];

  for (int step=0; step<LSEQ; ++step){
    int cd[2][4];
    #pragma unroll
    for (int mt=0;mt<2;++mt)
      #pragma unroll
      for (int q=0;q<4;++q) cd[mt][q] = codes_s[mt*16+g*4+q];

    // ===== phase ZR: z,r GEMMs on h(step) (buf0), depth-2 rotation =====
    {
      s8b zP[2][4], rP[2][4], aP[2][2];
      #pragma unroll
      for (int i=0;i<4;++i){
        zP[0][i]=BZ[tbase[i]];      rP[0][i]=BR[tbase[i]];
        zP[1][i]=BZ[tbase[i]+64];   rP[1][i]=BR[tbase[i]+64];
      }
      aP[0][0] = *(const s8b*)&buf0[lm][g*8];
      aP[0][1] = *(const s8b*)&buf0[16+lm][g*8];
      aP[1][0] = *(const s8b*)&buf0[lm][32+g*8];
      aP[1][1] = *(const s8b*)&buf0[16+lm][32+g*8];
      #pragma unroll
      for (int i=0;i<4;++i){
        #pragma unroll
        for (int mt=0;mt<2;++mt){ za[i][mt]=f4zero(); ra[i][mt]=f4zero(); }
      }
      #pragma unroll
      for (int kc=0;kc<16;++kc){
        const int cur = kc&1;
        #pragma unroll
        for (int i=0;i<4;++i){
          za[i][0]=MFMA16(aP[cur][0],zP[cur][i],za[i][0]);
          za[i][1]=MFMA16(aP[cur][1],zP[cur][i],za[i][1]);
          ra[i][0]=MFMA16(aP[cur][0],rP[cur][i],ra[i][0]);
          ra[i][1]=MFMA16(aP[cur][1],rP[cur][i],ra[i][1]);
        }
        if (kc<14){
          #pragma unroll
          for (int i=0;i<4;++i){
            zP[cur][i]=BZ[tbase[i]+(kc+2)*64];
            rP[cur][i]=BR[tbase[i]+(kc+2)*64];
          }
          aP[cur][0] = *(const s8b*)&buf0[lm][(kc+2)*32+g*8];
          aP[cur][1] = *(const s8b*)&buf0[16+lm][(kc+2)*32+g*8];
        }
      }
    }
    // ---- gh epilogue (z kept in za) ----
    #pragma unroll
    for (int i=0;i<4;++i){
      const int col=(4*w+i)*16+lm;
      #pragma unroll
      for (int mt=0;mt<2;++mt)
        #pragma unroll
        for (int q=0;q<4;++q){
          float zv = sigf(za[i][mt][q] + bf2f(wxb_s[0][cd[mt][q]][col]));
          float rv = sigf(ra[i][mt][q] + bf2f(wxb_s[1][cd[mt][q]][col]));
          za[i][mt][q] = zv;
          buf1[mt*16+g*4+q][col] = (short)f2bf(rv * hO[i][mt][q]);
        }
    }
    __syncthreads();   // gh visible

    // ===== phase C: candidate GEMM on gh (buf1), depth-2 rotation =====
    {
      s8b hP[2][4], aP[2][2];
      #pragma unroll
      for (int i=0;i<4;++i){
        hP[0][i]=BH[tbase[i]];
        hP[1][i]=BH[tbase[i]+64];
      }
      aP[0][0] = *(const s8b*)&buf1[lm][g*8];
      aP[0][1] = *(const s8b*)&buf1[16+lm][g*8];
      aP[1][0] = *(const s8b*)&buf1[lm][32+g*8];
      aP[1][1] = *(const s8b*)&buf1[16+lm][32+g*8];
      #pragma unroll
      for (int i=0;i<4;++i){
        #pragma unroll
        for (int mt=0;mt<2;++mt) ra[i][mt]=f4zero();
      }
      #pragma unroll
      for (int kc=0;kc<16;++kc){
        const int cur = kc&1;
        #pragma unroll
        for (int i=0;i<4;++i){
          ra[i][0]=MFMA16(aP[cur][0],hP[cur][i],ra[i][0]);
          ra[i][1]=MFMA16(aP[cur][1],hP[cur][i],ra[i][1]);
        }
        if (kc<14){
          #pragma unroll
          for (int i=0;i<4;++i) hP[cur][i]=BH[tbase[i]+(kc+2)*64];
          aP[cur][0] = *(const s8b*)&buf1[lm][(kc+2)*32+g*8];
          aP[cur][1] = *(const s8b*)&buf1[16+lm][(kc+2)*32+g*8];
        }
      }
    }
    // ---- h update ----
    #pragma unroll
    for (int i=0;i<4;++i){
      const int col=(4*w+i)*16+lm;
      #pragma unroll
      for (int mt=0;mt<2;++mt)
        #pragma unroll
        for (int q=0;q<4;++q){
          float pre = tanhf_fast(ra[i][mt][q] + bf2f(wxb_s[2][cd[mt][q]][col]));
          float zv  = za[i][mt][q];
          float hn2 = (1.f - zv)*hO[i][mt][q] + zv*pre;
          hO[i][mt][q] = hn2;
          buf0[mt*16+g*4+q][col] = (short)f2bf(hn2);
        }
    }
    __syncthreads();   // h(step+1) visible

    // ===== phase N: nuc GEMM on h(step+1) (buf0), depth-2 rotation =====
    {
      s8b nP[2][4], aP[2][2];
      #pragma unroll
      for (int i=0;i<4;++i){
        nP[0][i]=BN[tbase[i]];
        nP[1][i]=BN[tbase[i]+64];
      }
      aP[0][0] = *(const s8b*)&buf0[lm][g*8];
      aP[0][1] = *(const s8b*)&buf0[16+lm][g*8];
      aP[1][0] = *(const s8b*)&buf0[lm][32+g*8];
      aP[1][1] = *(const s8b*)&buf0[16+lm][32+g*8];
      #pragma unroll
      for (int i=0;i<4;++i){
        #pragma unroll
        for (int mt=0;mt<2;++mt) ra[i][mt]=f4zero();
      }
      #pragma unroll
      for (int kc=0;kc<16;++kc){
        const int cur = kc&1;
        #pragma unroll
        for (int i=0;i<4;++i){
          ra[i][0]=MFMA16(aP[cur][0],nP[cur][i],ra[i][0]);
          ra[i][1]=MFMA16(aP[cur][1],nP[cur][i],ra[i][1]);
        }
        if (kc<14){
          #pragma unroll
          for (int i=0;i<4;++i) nP[cur][i]=BN[tbase[i]+(kc+2)*64];
          aP[cur][0] = *(const s8b*)&buf0[lm][(kc+2)*32+g*8];
          aP[cur][1] = *(const s8b*)&buf0[16+lm][(kc+2)*32+g*8];
        }
      }
    }
    // ---- nuc epilogue: relu + 5-col matvec + reduce ----
    {
      float p[2][4][NNUC];
      #pragma unroll
      for (int mt=0;mt<2;++mt)
        #pragma unroll
        for (int q=0;q<4;++q)
          #pragma unroll
          for (int j=0;j<NNUC;++j) p[mt][q][j]=0.f;
      #pragma unroll
      for (int i=0;i<4;++i){
        const int col=(4*w+i)*16+lm;
        #pragma unroll
        for (int mt=0;mt<2;++mt)
          #pragma unroll
          for (int q=0;q<4;++q){
            float lv = (q&1) ? bfhi(lpk[i][mt][q>>1]) : bflo(lpk[i][mt][q>>1]);
            float hid = fmaxf(ra[i][mt][q] + lv, 0.f);
            #pragma unroll
            for (int j=0;j<NNUC;++j) p[mt][q][j] = fmaf(hid, bf2f(wns_s[j][col]), p[mt][q][j]);
          }
      }
      #pragma unroll
      for (int s=8;s>=1;s>>=1){
        #pragma unroll
        for (int mt=0;mt<2;++mt)
          #pragma unroll
          for (int q=0;q<4;++q)
            #pragma unroll
            for (int j=0;j<NNUC;++j) p[mt][q][j] += __shfl_xor(p[mt][q][j], s);
      }
      if (lm==0){
        #pragma unroll
        for (int mt=0;mt<2;++mt)
          #pragma unroll
          for (int q=0;q<4;++q)
            #pragma unroll
            for (int j=0;j<NNUC;++j) redbuf[w][mt*16+g*4+q][j] = p[mt][q][j];
      }
    }
    if (t<32 && step+1<LSEQ) codes_s[t] = nuc_idx[(size_t)(n0+t)*LSEQ + step + 1];
    __syncthreads();   // redbuf + next codes visible
    if (t < 32*NNUC){
      int r2 = t/NNUC, j = t - r2*NNUC;
      float s2 = 0.f;
      #pragma unroll
      for (int ww=0;ww<8;++ww) s2 += redbuf[ww][r2][j];
      out_nuc[((size_t)(n0+r2)*LSEQ + step)*NNUC + j] = s2 + bn;
    }
  }

  // ---- hpn head on final h (buf0) ----
  {
    const s8b* fhB = (const s8b*)fhpn;
    f4 hacc[4][2];
    #pragma unroll
    for (int i=0;i<4;++i)
      #pragma unroll
      for (int mt=0;mt<2;++mt) hacc[i][mt]=f4zero();
    #pragma unroll
    for (int kc=0;kc<16;++kc){
      s8b a0 = *(const s8b*)&buf0[lm][kc*32+g*8];
      s8b a1 = *(const s8b*)&buf0[16+lm][kc*32+g*8];
      #pragma unroll
      for (int i=0;i<4;++i){
        s8b wf = fhB[(size_t)(((4*w+i)*16+kc)*64) + l];
        hacc[i][0] = MFMA16(a0, wf, hacc[i][0]);
        hacc[i][1] = MFMA16(a1, wf, hacc[i][1]);
      }
    }
    float p[2][4][NHPN];
    #pragma unroll
    for (int mt=0;mt<2;++mt)
      #pragma unroll
      for (int q=0;q<4;++q)
        #pragma unroll
        for (int j=0;j<NHPN;++j) p[mt][q][j]=0.f;
    #pragma unroll
    for (int i=0;i<4;++i){
      const int col=(4*w+i)*16+lm;
      float bnl = b_hpn_nl[col];
      #pragma unroll
      for (int mt=0;mt<2;++mt)
        #pragma unroll
        for (int q=0;q<4;++q){
          float hid = fmaxf(hacc[i][mt][q] + bnl, 0.f);
          #pragma unroll
          for (int j=0;j<NHPN;++j) p[mt][q][j] = fmaf(hid, w_hpn[(size_t)j*HD + col], p[mt][q][j]);
        }
    }
    #pragma unroll
    for (int s=8;s>=1;s>>=1){
      #pragma unroll
      for (int mt=0;mt<2;++mt)
        #pragma unroll
        for (int q=0;q<4;++q)
          #pragma unroll
          for (int j=0;j<NHPN;++j) p[mt][q][j] += __shfl_xor(p[mt][q][j], s);
    }
    __syncthreads();   // step-63 redbuf reads done
    if (lm==0){
      #pragma unroll
      for (int mt=0;mt<2;++mt)
        #pragma unroll
        for (int q=0;q<4;++q)
          #pragma unroll
          for (int j=0;j<NHPN;++j) redbuf[w][mt*16+g*4+q][j] = p[mt][q][j];
    }
    __syncthreads();
    if (t < 32*NHPN){
      int r2 = t/NHPN, j = t - r2*NHPN;
      float s2 = 0.f;
      #pragma unroll
      for (int ww=0;ww<8;++ww) s2 += redbuf[ww][r2][j];
      out_hpn[(size_t)(n0+r2)*NHPN + j] = s2 + b_hpn[j];
    }
  }

  // ---- write new_h from fp32 master ----
  #pragma unroll
  for (int i=0;i<4;++i){
    int col=(4*w+i)*16+lm;
    #pragma unroll
    for (int mt=0;mt<2;++mt)
      #pragma unroll
      for (int q=0;q<4;++q)
        out_newh[(size_t)(n0+mt*16+g*4+q)*HD + col] = hO[i][mt][q];
  }
}

// ---------------- host ----------------
extern "C" void kernel_launch(void* const* d_in, const int* in_sizes, int n_in,
                              void* d_out, int out_size, void* d_ws, size_t ws_size,
                              hipStream_t stream_){
  (void)in_sizes; (void)n_in; (void)out_size; (void)ws_size;
  const int*   hpn_idx      = (const int*)d_in[0];
  const int*   nuc_idx      = (const int*)d_in[1];
  const float* h_nei        = (const float*)d_in[2];
  const float* graph_latent = (const float*)d_in[3];
  const float* Wz_mp=(const float*)d_in[4];  const float* bz_mp=(const float*)d_in[5];
  const float* Wr_mp=(const float*)d_in[6];  const float* br_mp=(const float*)d_in[7];
  const float* Ur_mp=(const float*)d_in[8];
  const float* Wh_mp=(const float*)d_in[9];  const float* bh_mp=(const float*)d_in[10];
  const float* Wz_nuc=(const float*)d_in[11]; const float* bz_nuc=(const float*)d_in[12];
  const float* Wr_nuc=(const float*)d_in[13]; const float* br_nuc=(const float*)d_in[14];
  const float* Wh_nuc=(const float*)d_in[15]; const float* bh_nuc=(const float*)d_in[16];
  const float* W_hpn_nl=(const float*)d_in[17]; const float* b_hpn_nl=(const float*)d_in[18];
  const float* W_hpn=(const float*)d_in[19];  const float* b_hpn=(const float*)d_in[20];
  const float* W_nuc_nl=(const float*)d_in[21]; const float* b_nuc_nl=(const float*)d_in[22];
  const float* W_nuc=(const float*)d_in[23];  const float* b_nuc=(const float*)d_in[24];
  const float* W_topo_nl=(const float*)d_in[25]; const float* b_topo_nl=(const float*)d_in[26];
  const float* W_topo=(const float*)d_in[27]; const float* b_topo=(const float*)d_in[28];

  float* ws = (float*)d_ws;
  size_t off = 0;
  auto take = [&](size_t nfl){ float* p = ws + off; off += nfl; return p; };
  // graphgru fp32 transposed weights
  float* wt_z_mp   = take((size_t)HD*HD);
  float* wt_ur     = take((size_t)HD*HD);
  float* wt_h_mp   = take((size_t)HD*HD);
  float* wt_topo   = take((size_t)HD*HD);
  float* wt_nl_lat = take((size_t)LATD*HD);
  float* wx_z_mp   = take((size_t)NHPN*HD);
  float* wx_h_mp   = take((size_t)NHPN*HD);
  float* wx_r_mp   = take((size_t)NHPN*HD);
  // scan bf16 fragment weights
  short* fz   = (short*)take((size_t)HD*HD/2);
  short* fr   = (short*)take((size_t)HD*HD/2);
  short* fh   = (short*)take((size_t)HD*HD/2);
  short* fnuc = (short*)take((size_t)HD*HD/2);
  short* fhpn = (short*)take((size_t)HD*HD/2);
  float* wxbz = take((size_t)NNUC*HD);
  float* wxbr = take((size_t)NNUC*HD);
  float* wxbh = take((size_t)NNUC*HD);
  float* latp = take((size_t)NROWS*HD);
  float* msg  = take((size_t)NROWS*HD);

  float* out       = (float*)d_out;
  float* out_newh  = out;
  float* out_hpn   = out + (size_t)NROWS*HD;
  float* out_nuc   = out_hpn + (size_t)NROWS*NHPN;
  float* out_stop  = out_nuc + (size_t)NROWS*LSEQ*NNUC;

  auto T = [&](const float* src, float* dst, int sc, int coff, int nh){
    int total = nh*HD;
    transpose_w<<<(total+255)/256, 256, 0, stream_>>>(src, dst, sc, coff, nh);
  };
  T(Wz_mp,    wt_z_mp,   HD+NHPN, NHPN, HD);
  T(Wz_mp,    wx_z_mp,   HD+NHPN, 0,    NHPN);
  T(Wr_mp,    wx_r_mp,   NHPN,    0,    NHPN);
  T(Ur_mp,    wt_ur,     HD,      0,    HD);
  T(Wh_mp,    wt_h_mp,   HD+NHPN, NHPN, HD);
  T(Wh_mp,    wx_h_mp,   HD+NHPN, 0,    NHPN);
  T(W_topo_nl,wt_topo,   HD,      0,    HD);
  T(W_nuc_nl, wt_nl_lat, HD+LATD, HD,   LATD);

  const int FB = (HD*HD+255)/256;
  fragprep_k<<<FB,256,0,stream_>>>(Wz_nuc,   fz,   HD+NNUC, NNUC);
  fragprep_k<<<FB,256,0,stream_>>>(Wr_nuc,   fr,   HD+NNUC, NNUC);
  fragprep_k<<<FB,256,0,stream_>>>(Wh_nuc,   fh,   HD+NNUC, NNUC);
  fragprep_k<<<FB,256,0,stream_>>>(W_nuc_nl, fnuc, HD+LATD, 0);
  fragprep_k<<<FB,256,0,stream_>>>(W_hpn_nl, fhpn, HD,      0);

  const int WB = (NNUC*HD+255)/256;
  wxbprep_k<<<WB,256,0,stream_>>>(Wz_nuc, bz_nuc, wxbz, HD+NNUC);
  wxbprep_k<<<WB,256,0,stream_>>>(Wr_nuc, br_nuc, wxbr, HD+NNUC);
  wxbprep_k<<<WB,256,0,stream_>>>(Wh_nuc, bh_nuc, wxbh, HD+NNUC);

  latp_k<<<NROWS/16, 512, 0, stream_>>>(graph_latent, wt_nl_lat, b_nuc_nl, latp);

  graphgru_k<<<NROWS/8, 512, 0, stream_>>>(
      hpn_idx, h_nei,
      wt_z_mp, wx_z_mp, bz_mp,
      wx_r_mp, br_mp, wt_ur,
      wt_h_mp, wx_h_mp, bh_mp,
      wt_topo, b_topo_nl, W_topo, b_topo,
      msg, out_stop);

  scan_pipe_k<<<NROWS/32, 512, 0, stream_>>>(
      nuc_idx, msg,
      fz, fr, fh, fnuc, fhpn,
      wxbz, wxbr, wxbh, latp,
      W_nuc, b_nuc, b_hpn_nl, W_hpn, b_hpn,
      out_newh, out_hpn, out_nuc);
}

// Round 8
// 2480.537 us; speedup vs baseline: 2.6002x; 2.6002x over previous
//
#include <hip/hip_runtime.h>
#include <math.h>

#define NROWS 2048
#define KNEI  8
#define LSEQ  64
#define HD    512
#define HD4   128
#define LATD  128
#define NHPN  4
#define NNUC  5

typedef __attribute__((ext_vector_type(8))) short s8b;   // 8 bf16 (16B)
typedef __attribute__((ext_vector_type(4))) float f4;    // MFMA acc

#define MFMA16(a,b,c) __builtin_amdgcn_mfma_f32_16x16x32_bf16(a,b,c,0,0,0)

__device__ __forceinline__ f4 f4zero(){ f4 z; z[0]=0.f; z[1]=0.f; z[2]=0.f; z[3]=0.f; return z; }
__device__ __forceinline__ float sigf(float x){ return __fdividef(1.0f, 1.0f + __expf(-x)); }
__device__ __forceinline__ float tanhf_fast(float x){
  float e = __expf(-2.0f*fabsf(x));
  float t = __fdividef(1.0f - e, 1.0f + e);
  return x >= 0.f ? t : -t;
}
__device__ __forceinline__ unsigned short f2bf(float x){
  union{float f; unsigned u;} v; v.f = x;
  unsigned r = (v.u + 0x7FFFu + ((v.u>>16)&1u)) >> 16;
  return (unsigned short)r;
}

__device__ __forceinline__ void dma16(const short* g, const short* l){
  __builtin_amdgcn_global_load_lds(
      (const __attribute__((address_space(1))) void*)(unsigned long long)g,
      (__attribute__((address_space(3))) void*)(unsigned long long)l,
      16, 0, 0);
}

// ----- fp32 helpers for graphgru -----
__device__ __forceinline__ void fma4(float4& a, float s, float4 w){
  a.x = fmaf(s,w.x,a.x); a.y = fmaf(s,w.y,a.y); a.z = fmaf(s,w.z,a.z); a.w = fmaf(s,w.w,a.w);
}
__device__ __forceinline__ void add4(float4& a, float4 b){ a.x+=b.x; a.y+=b.y; a.z+=b.z; a.w+=b.w; }
__device__ __forceinline__ float4 sig4(float4 v){
  return make_float4(1.f/(1.f+__expf(-v.x)),1.f/(1.f+__expf(-v.y)),1.f/(1.f+__expf(-v.z)),1.f/(1.f+__expf(-v.w)));
}
__device__ __forceinline__ float4 relu4(float4 v){ return make_float4(fmaxf(v.x,0.f),fmaxf(v.y,0.f),fmaxf(v.z,0.f),fmaxf(v.w,0.f)); }
__device__ __forceinline__ float dot4(float4 a, float4 b){ return a.x*b.x + a.y*b.y + a.z*b.z + a.w*b.w; }
__device__ __forceinline__ float4 gate_mul(float4 tv, float4 e){
  return make_float4((1.f/(1.f+__expf(-tv.x)))*e.x,(1.f/(1.f+__expf(-tv.y)))*e.y,
                     (1.f/(1.f+__expf(-tv.z)))*e.z,(1.f/(1.f+__expf(-tv.w)))*e.w);
}
__device__ __forceinline__ float4 gru_out(float4 z, float4 hprev, float4 pre){
  return make_float4((1.f-z.x)*hprev.x + z.x*tanhf(pre.x),
                     (1.f-z.y)*hprev.y + z.y*tanhf(pre.y),
                     (1.f-z.z)*hprev.z + z.z*tanhf(pre.z),
                     (1.f-z.w)*hprev.w + z.w*tanhf(pre.w));
}

// ---------------- prep kernels ----------------

__global__ void transpose_w(const float* __restrict__ src, float* __restrict__ dst,
                            int src_cols, int col_off, int nh){
  int idx = blockIdx.x*256 + threadIdx.x;
  if (idx >= nh*HD) return;
  int h = idx / HD, o = idx - h*HD;
  dst[idx] = src[o*src_cols + col_off + h];
}

// B-frag layout (per 16x16x32 tile, 1KB): dst[tile*512 + l*8 + j] = W[n][k]
// tile = ot*16+kc ; n = ot*16+(l&15) ; k = kc*32+(l>>4)*8+j
__global__ void fragprep_k(const float* __restrict__ W, short* __restrict__ dst,
                           int src_cols, int col_off){
  int idx = blockIdx.x*256 + threadIdx.x;
  if (idx >= HD*HD) return;
  int j = idx&7, l = (idx>>3)&63, tile = idx>>9;
  int kc = tile&15, ot = tile>>4;
  int row = ot*16 + (l&15), k = kc*32 + (l>>4)*8 + j;
  dst[idx] = (short)f2bf(W[(size_t)row*src_cols + col_off + k]);
}

// wxb[c*HD + n] = W[n][c] + b[n]
__global__ void wxbprep_k(const float* __restrict__ W, const float* __restrict__ b,
                          float* __restrict__ dst, int src_cols){
  int idx = blockIdx.x*256 + threadIdx.x;
  if (idx >= NNUC*HD) return;
  int c = idx/HD, n = idx - c*HD;
  dst[idx] = W[(size_t)n*src_cols + c] + b[n];
}

__global__ void bf16cast_k(const float* __restrict__ src, short* __restrict__ dst){
  int i = blockIdx.x*256 + threadIdx.x;
  dst[i] = (short)f2bf(src[i]);
}

// latp[n][o] = b_nl[o] + sum_q gl[n][q]*wtlat[q*HD+o]
__global__ __launch_bounds__(512) void latp_k(const float* __restrict__ gl, const float* __restrict__ wtlat,
                     const float* __restrict__ bnl, float* __restrict__ latp){
  __shared__ float gls[16][LATD];
  int b = blockIdx.x, t = threadIdx.x;
  for (int i=t;i<16*LATD;i+=512) gls[i/LATD][i%LATD] = gl[(size_t)(b*16)*LATD + i];
  __syncthreads();
  float acc[16];
  float bv = bnl[t];
  #pragma unroll
  for (int r=0;r<16;++r) acc[r]=bv;
  for (int q=0;q<LATD;++q){
    float wv = wtlat[(size_t)q*HD + t];
    #pragma unroll
    for (int r=0;r<16;++r) acc[r] = fmaf(gls[r][q], wv, acc[r]);
  }
  #pragma unroll
  for (int r=0;r<16;++r) latp[(size_t)(b*16+r)*HD + t] = acc[r];
}

// ---------------- GraphGRU (unchanged verified fp32 path) ----------------
__global__ __launch_bounds__(512) void graphgru_k(
    const int* __restrict__ hpn_idx, const float* __restrict__ h_nei,
    const float* __restrict__ wt_z, const float* __restrict__ wx_z, const float* __restrict__ bz,
    const float* __restrict__ wx_r, const float* __restrict__ br,
    const float* __restrict__ wt_ur,
    const float* __restrict__ wt_h, const float* __restrict__ wx_h, const float* __restrict__ bh,
    const float* __restrict__ wt_topo, const float* __restrict__ b_topo_nl,
    const float* __restrict__ w_topo, const float* __restrict__ b_topo,
    float* __restrict__ msg, float* __restrict__ out_stop)
{
  __shared__ float sumh[8][HD];
  __shared__ float hk[8][HD];
  __shared__ float sg[8][HD];
  __shared__ float red[8][2];
  const int t = threadIdx.x, lane = t&63, wv = t>>6;
  const int r0 = (wv>>1)<<1;
  const int oh = wv&1;
  const int ob4 = 64*oh + lane;
  const int n0 = blockIdx.x*8;
  float4* sumh4 = (float4*)(&sumh[0][0]);
  float4* hk4   = (float4*)(&hk[0][0]);
  float4* sg4   = (float4*)(&sg[0][0]);
  const float4* hn4 = (const float4*)h_nei;

  for (int idx=t; idx<8*HD4; idx+=512){
    int r = idx>>7, c = idx&127;
    size_t base = ((size_t)(n0+r))*KNEI*HD4 + c;
    float4 s = hn4[base];
    #pragma unroll
    for (int k=1;k<KNEI;++k) add4(s, hn4[base + (size_t)k*HD4]);
    sumh4[idx] = s;
  }
  __syncthreads();

  const int hp0 = hpn_idx[n0+r0], hp1 = hpn_idx[n0+r0+1];
  const float4* bz4 = (const float4*)bz;
  const float4* wxz4 = (const float4*)wx_z;
  const float4* wtz4 = (const float4*)wt_z;
  float4 z0 = bz4[ob4]; add4(z0, wxz4[hp0*HD4 + ob4]);
  float4 z1 = bz4[ob4]; add4(z1, wxz4[hp1*HD4 + ob4]);
  for (int h=0;h<HD;++h){
    float a0 = sumh[r0][h], a1 = sumh[r0+1][h];
    float4 w = wtz4[h*HD4 + ob4];
    fma4(z0,a0,w); fma4(z1,a1,w);
  }
  z0 = sig4(z0); z1 = sig4(z1);

  const float4* br4 = (const float4*)br;
  const float4* wxr4 = (const float4*)wx_r;
  const float4* wtur4 = (const float4*)wt_ur;
  float4 rb0 = br4[ob4]; add4(rb0, wxr4[hp0*HD4 + ob4]);
  float4 rb1 = br4[ob4]; add4(rb1, wxr4[hp1*HD4 + ob4]);
  float4 sg0 = make_float4(0.f,0.f,0.f,0.f), sg1 = sg0;
  for (int k=0;k<KNEI;++k){
    __syncthreads();
    for (int idx=t; idx<8*HD4; idx+=512){
      int r = idx>>7, c = idx&127;
      hk4[idx] = hn4[((size_t)(n0+r)*KNEI + (size_t)k)*HD4 + c];
    }
    __syncthreads();
    float4 t0 = rb0, t1 = rb1;
    for (int h=0;h<HD;++h){
      float a0 = hk[r0][h], a1 = hk[r0+1][h];
      float4 w = wtur4[h*HD4 + ob4];
      fma4(t0,a0,w); fma4(t1,a1,w);
    }
    float4 e0 = hk4[r0*HD4 + ob4], e1 = hk4[(r0+1)*HD4 + ob4];
    add4(sg0, gate_mul(t0, e0));
    add4(sg1, gate_mul(t1, e1));
  }
  __syncthreads();
  sg4[r0*HD4+ob4] = sg0; sg4[(r0+1)*HD4+ob4] = sg1;
  __syncthreads();

  const float4* bh4 = (const float4*)bh;
  const float4* wxh4 = (const float4*)wx_h;
  const float4* wth4 = (const float4*)wt_h;
  float4 p0 = bh4[ob4]; add4(p0, wxh4[hp0*HD4+ob4]);
  float4 p1 = bh4[ob4]; add4(p1, wxh4[hp1*HD4+ob4]);
  for (int h=0;h<HD;++h){
    float a0 = sg[r0][h], a1 = sg[r0+1][h];
    float4 w = wth4[h*HD4+ob4];
    fma4(p0,a0,w); fma4(p1,a1,w);
  }
  float4 sh0 = sumh4[r0*HD4+ob4], sh1 = sumh4[(r0+1)*HD4+ob4];
  float4 m0 = gru_out(z0, sh0, p0);
  float4 m1 = gru_out(z1, sh1, p1);
  ((float4*)msg)[(size_t)(n0+r0)*HD4 + ob4] = m0;
  ((float4*)msg)[(size_t)(n0+r0+1)*HD4 + ob4] = m1;
  __syncthreads();
  sg4[r0*HD4+ob4] = m0; sg4[(r0+1)*HD4+ob4] = m1;
  __syncthreads();

  const float4* btnl4 = (const float4*)b_topo_nl;
  const float4* wttopo4 = (const float4*)wt_topo;
  float4 q0 = btnl4[ob4], q1 = btnl4[ob4];
  for (int h=0;h<HD;++h){
    float a0 = sg[r0][h], a1 = sg[r0+1][h];
    float4 w = wttopo4[h*HD4+ob4];
    fma4(q0,a0,w); fma4(q1,a1,w);
  }
  float4 wt4v = ((const float4*)w_topo)[ob4];
  float th0 = dot4(relu4(q0), wt4v);
  float th1 = dot4(relu4(q1), wt4v);
  #pragma unroll
  for (int s=32;s>0;s>>=1){ th0 += __shfl_down(th0,s); th1 += __shfl_down(th1,s); }
  if (lane==0){ red[r0][oh]=th0; red[r0+1][oh]=th1; }
  __syncthreads();
  if (t<8) out_stop[n0+t] = red[t][0] + red[t][1] + b_topo[0];
}

// ---------------- scan step kernel A: z, r, nuc GEMMs on h(t) ----------------
// grid (32 row-tiles x 12 col-groups), 512 threads. cg>>2: 0=z,1=r,2=nuc.
// Weights LDS-double-buffered via global_load_lds (m97 pattern); h-frags in regs.
__global__ __launch_bounds__(512) void zrnuc_k(
    int t, const int* __restrict__ nuc_idx,
    const short* __restrict__ fz, const short* __restrict__ fr, const short* __restrict__ fnuc,
    const short* __restrict__ hB, const float* __restrict__ hF,
    const float* __restrict__ wxbz, const float* __restrict__ wxbr,
    const float* __restrict__ latp, const float* __restrict__ w_nuc,
    float* __restrict__ zF, short* __restrict__ ghB, float* __restrict__ nucp)
{
  const int cg = blockIdx.y;
  const int mat = cg>>2;
  if (t==0 && mat==2) return;        // no hs[-1]
  __shared__ __align__(16) short stage[2][4096];
  __shared__ int codes_s[64];
  const int tt = threadIdx.x, l = tt&63, w = tt>>6, lm = l&15, g = l>>4;
  const int rt = blockIdx.x, row0 = rt*64;
  const short* frag = (mat==0)?fz:((mat==1)?fr:fnuc);
  const int otb = (cg&3)*8;
  if (tt<64) codes_s[tt] = nuc_idx[(size_t)(row0+tt)*LSEQ + t];
  const int mt = w>>1, nh2 = w&1;
  // preload 16 A-frags (16 rows of h, this wave's mtile)
  s8b af[16];
  {
    const s8b* hrow = (const s8b*)(hB + (size_t)(row0 + mt*16 + lm)*HD);
    #pragma unroll
    for (int kc=0;kc<16;++kc) af[kc] = hrow[kc*4 + g];
  }
  dma16(frag + ((size_t)((otb + w)*16))*512 + (size_t)l*8, &stage[0][tt*8]);
  asm volatile("s_waitcnt vmcnt(0)" ::: "memory");
  __syncthreads();
  f4 acc[4];
  #pragma unroll
  for (int i=0;i<4;++i) acc[i]=f4zero();
  #pragma unroll
  for (int kc=0;kc<16;++kc){
    const int cur = kc&1;
    if (kc<15)
      dma16(frag + ((size_t)((otb + w)*16 + kc+1))*512 + (size_t)l*8, &stage[cur^1][tt*8]);
    #pragma unroll
    for (int i=0;i<4;++i){
      s8b b = ((const s8b*)&stage[cur][(nh2*4+i)*512])[l];
      acc[i] = MFMA16(af[kc], b, acc[i]);
    }
    asm volatile("s_waitcnt vmcnt(0) lgkmcnt(0)" ::: "memory");
    __builtin_amdgcn_s_barrier();
  }
  // epilogues (D: row=row0+mt*16+g*4+q, col=(cg&3)*128+(nh2*4+i)*16+lm)
  const int colb = (cg&3)*128;
  if (mat==0){
    #pragma unroll
    for (int i=0;i<4;++i){
      const int col = colb + (nh2*4+i)*16 + lm;
      #pragma unroll
      for (int q=0;q<4;++q){
        const int r = mt*16 + g*4 + q;
        float zv = sigf(acc[i][q] + wxbz[codes_s[r]*HD + col]);
        zF[(size_t)(row0+r)*HD + col] = zv;
      }
    }
  } else if (mat==1){
    #pragma unroll
    for (int i=0;i<4;++i){
      const int col = colb + (nh2*4+i)*16 + lm;
      #pragma unroll
      for (int q=0;q<4;++q){
        const int r = mt*16 + g*4 + q;
        float rv = sigf(acc[i][q] + wxbr[codes_s[r]*HD + col]);
        ghB[(size_t)(row0+r)*HD + col] = (short)f2bf(rv * hF[(size_t)(row0+r)*HD + col]);
      }
    }
  } else {
    float p[4][NNUC];
    #pragma unroll
    for (int q=0;q<4;++q)
      #pragma unroll
      for (int j=0;j<NNUC;++j) p[q][j]=0.f;
    #pragma unroll
    for (int i=0;i<4;++i){
      const int col = colb + (nh2*4+i)*16 + lm;
      #pragma unroll
      for (int q=0;q<4;++q){
        const int r = mt*16 + g*4 + q;
        float hid = fmaxf(acc[i][q] + latp[(size_t)(row0+r)*HD + col], 0.f);
        #pragma unroll
        for (int j=0;j<NNUC;++j) p[q][j] = fmaf(hid, w_nuc[(size_t)j*HD + col], p[q][j]);
      }
    }
    #pragma unroll
    for (int s=1;s<16;s<<=1)
      #pragma unroll
      for (int q=0;q<4;++q)
        #pragma unroll
        for (int j=0;j<NNUC;++j) p[q][j] += __shfl_xor(p[q][j], s);
    if (lm==0){
      const int slab = (cg&3)*2 + nh2;
      #pragma unroll
      for (int q=0;q<4;++q){
        const int row = row0 + mt*16 + g*4 + q;
        #pragma unroll
        for (int j=0;j<NNUC;++j)
          nucp[((size_t)slab*NROWS + row)*NNUC + j] = p[q][j];
      }
    }
  }
}

// ---------------- scan step kernel B: candidate GEMM + h update ----------------
// grid (64 row-tiles x 4 col-groups), 512 threads.
__global__ __launch_bounds__(512) void cand_k(
    int t, const int* __restrict__ nuc_idx,
    const short* __restrict__ fh,
    const short* __restrict__ ghB,
    const float* __restrict__ wxbh,
    const float* __restrict__ zF, float* __restrict__ hF, short* __restrict__ hB,
    const float* __restrict__ nucp, const float* __restrict__ b_nuc,
    float* __restrict__ out_nuc)
{
  __shared__ __align__(16) short stage[2][4096];
  __shared__ int codes_s[32];
  const int tt = threadIdx.x, l = tt&63, w = tt>>6, lm = l&15, g = l>>4;
  const int rt = blockIdx.x, row0 = rt*32, cg = blockIdx.y;
  if (tt<32) codes_s[tt] = nuc_idx[(size_t)(row0+tt)*LSEQ + t];
  const int mt = w>>2, ntp = w&3;
  s8b af[16];
  {
    const s8b* grow = (const s8b*)(ghB + (size_t)(row0 + mt*16 + lm)*HD);
    #pragma unroll
    for (int kc=0;kc<16;++kc) af[kc] = grow[kc*4 + g];
  }
  dma16(fh + ((size_t)((cg*8 + w)*16))*512 + (size_t)l*8, &stage[0][tt*8]);
  asm volatile("s_waitcnt vmcnt(0)" ::: "memory");
  __syncthreads();
  f4 acc[2]; acc[0]=f4zero(); acc[1]=f4zero();
  #pragma unroll
  for (int kc=0;kc<16;++kc){
    const int cur = kc&1;
    if (kc<15)
      dma16(fh + ((size_t)((cg*8 + w)*16 + kc+1))*512 + (size_t)l*8, &stage[cur^1][tt*8]);
    #pragma unroll
    for (int i2=0;i2<2;++i2){
      s8b b = ((const s8b*)&stage[cur][(ntp*2+i2)*512])[l];
      acc[i2] = MFMA16(af[kc], b, acc[i2]);
    }
    asm volatile("s_waitcnt vmcnt(0) lgkmcnt(0)" ::: "memory");
    __builtin_amdgcn_s_barrier();
  }
  #pragma unroll
  for (int i2=0;i2<2;++i2){
    const int col = cg*128 + (ntp*2+i2)*16 + lm;
    #pragma unroll
    for (int q=0;q<4;++q){
      const int r = mt*16 + g*4 + q;
      const size_t idx = (size_t)(row0+r)*HD + col;
      float pre = tanhf_fast(acc[i2][q] + wxbh[codes_s[r]*HD + col]);
      float zv = zF[idx];
      float hn = (1.f - zv)*hF[idx] + zv*pre;
      hF[idx] = hn;
      hB[idx] = (short)f2bf(hn);
    }
  }
  // reduce nuc partials for l = t-1 (written by zrnuc_k(t))
  if (t > 0 && cg == 0 && tt < 32*NNUC){
    int rr = tt/NNUC, j = tt - rr*NNUC;
    int row = row0 + rr;
    float s2 = b_nuc[j];
    #pragma unroll
    for (int s8=0;s8<8;++s8) s2 += nucp[((size_t)s8*NROWS + row)*NNUC + j];
    out_nuc[((size_t)row*LSEQ + (t-1))*NNUC + j] = s2;
  }
}

// ---------------- tail heads: nuc(l=63) + hpn on h(64) ----------------
// grid (64 row-tiles x 8): cg>>2: 0=nuc, 1=hpn; cols (cg&3)*128.
__global__ __launch_bounds__(512) void heads_k(
    const short* __restrict__ fnuc, const short* __restrict__ fhpn,
    const short* __restrict__ hB,
    const float* __restrict__ latp, const float* __restrict__ w_nuc,
    const float* __restrict__ b_hpn_nl, const float* __restrict__ w_hpn,
    float* __restrict__ nucpH, float* __restrict__ hpnp)
{
  __shared__ __align__(16) short stage[2][4096];
  const int tt = threadIdx.x, l = tt&63, w = tt>>6, lm = l&15, g = l>>4;
  const int rt = blockIdx.x, row0 = rt*32, cg = blockIdx.y;
  const int mat = cg>>2;
  const short* frag = mat ? fhpn : fnuc;
  const int mt = w>>2, ntp = w&3;
  s8b af[16];
  {
    const s8b* hrow = (const s8b*)(hB + (size_t)(row0 + mt*16 + lm)*HD);
    #pragma unroll
    for (int kc=0;kc<16;++kc) af[kc] = hrow[kc*4 + g];
  }
  dma16(frag + ((size_t)(((cg&3)*8 + w)*16))*512 + (size_t)l*8, &stage[0][tt*8]);
  asm volatile("s_waitcnt vmcnt(0)" ::: "memory");
  __syncthreads();
  f4 acc[2]; acc[0]=f4zero(); acc[1]=f4zero();
  #pragma unroll
  for (int kc=0;kc<16;++kc){
    const int cur = kc&1;
    if (kc<15)
      dma16(frag + ((size_t)(((cg&3)*8 + w)*16 + kc+1))*512 + (size_t)l*8, &stage[cur^1][tt*8]);
    #pragma unroll
    for (int i2=0;i2<2;++i2){
      s8b b = ((const s8b*)&stage[cur][(ntp*2+i2)*512])[l];
      acc[i2] = MFMA16(af[kc], b, acc[i2]);
    }
    asm volatile("s_waitcnt vmcnt(0) lgkmcnt(0)" ::: "memory");
    __builtin_amdgcn_s_barrier();
  }
  const int slab = (cg&3)*4 + ntp;
  if (mat==0){
    float p[4][NNUC];
    #pragma unroll
    for (int q=0;q<4;++q)
      #pragma unroll
      for (int j=0;j<NNUC;++j) p[q][j]=0.f;
    #pragma unroll
    for (int i2=0;i2<2;++i2){
      const int col = (cg&3)*128 + (ntp*2+i2)*16 + lm;
      #pragma unroll
      for (int q=0;q<4;++q){
        const int r = mt*16 + g*4 + q;
        float hid = fmaxf(acc[i2][q] + latp[(size_t)(row0+r)*HD + col], 0.f);
        #pragma unroll
        for (int j=0;j<NNUC;++j) p[q][j] = fmaf(hid, w_nuc[(size_t)j*HD + col], p[q][j]);
      }
    }
    #pragma unroll
    for (int s=1;s<16;s<<=1)
      #pragma unroll
      for (int q=0;q<4;++q)
        #pragma unroll
        for (int j=0;j<NNUC;++j) p[q][j] += __shfl_xor(p[q][j], s);
    if (lm==0){
      #pragma unroll
      for (int q=0;q<4;++q){
        const int row = row0 + mt*16 + g*4 + q;
        #pragma unroll
        for (int j=0;j<NNUC;++j)
          nucpH[((size_t)slab*NROWS + row)*NNUC + j] = p[q][j];
      }
    }
  } else {
    float p[4][NHPN];
    #pragma unroll
    for (int q=0;q<4;++q)
      #pragma unroll
      for (int j=0;j<NHPN;++j) p[q][j]=0.f;
    #pragma unroll
    for (int i2=0;i2<2;++i2){
      const int col = (cg&3)*128 + (ntp*2+i2)*16 + lm;
      float bnl = b_hpn_nl[col];
      #pragma unroll
      for (int q=0;q<4;++q){
        float hid = fmaxf(acc[i2][q] + bnl, 0.f);
        #pragma unroll
        for (int j=0;j<NHPN;++j) p[q][j] = fmaf(hid, w_hpn[(size_t)j*HD + col], p[q][j]);
      }
    }
    #pragma unroll
    for (int s=1;s<16;s<<=1)
      #pragma unroll
      for (int q=0;q<4;++q)
        #pragma unroll
        for (int j=0;j<NHPN;++j) p[q][j] += __shfl_xor(p[q][j], s);
    if (lm==0){
      #pragma unroll
      for (int q=0;q<4;++q){
        const int row = row0 + mt*16 + g*4 + q;
        #pragma unroll
        for (int j=0;j<NHPN;++j)
          hpnp[((size_t)slab*NROWS + row)*NHPN + j] = p[q][j];
      }
    }
  }
}

__global__ void final_red_k(const float* __restrict__ nucpH, const float* __restrict__ hpnp,
    const float* __restrict__ b_nuc, const float* __restrict__ b_hpn,
    const float* __restrict__ hF,
    float* __restrict__ out_newh, float* __restrict__ out_hpn, float* __restrict__ out_nuc)
{
  int gid = blockIdx.x*256 + threadIdx.x;   // grid 128x256 = 32768
  if (gid < NROWS*NNUC){
    int n = gid/NNUC, j = gid - n*NNUC;
    float s = b_nuc[j];
    #pragma unroll
    for (int s8=0;s8<16;++s8) s += nucpH[((size_t)s8*NROWS + n)*NNUC + j];
    out_nuc[((size_t)n*LSEQ + 63)*NNUC + j] = s;
  } else if (gid < NROWS*NNUC + NROWS*NHPN){
    int g2 = gid - NROWS*NNUC;
    int n = g2/NHPN, j = g2 - n*NHPN;
    float s = b_hpn[j];
    #pragma unroll
    for (int s8=0;s8<16;++s8) s += hpnp[((size_t)s8*NROWS + n)*NHPN + j];
    out_hpn[(size_t)n*NHPN + j] = s;
  }
  const float4* src = (const float4*)hF;
  float4* dst = (float4*)out_newh;
  for (int i = gid; i < NROWS*HD/4; i += 32768) dst[i] = src[i];
}

// ---------------- host ----------------
extern "C" void kernel_launch(void* const* d_in, const int* in_sizes, int n_in,
                              void* d_out, int out_size, void* d_ws, size_t ws_size,
                              hipStream_t stream_){
  (void)in_sizes; (void)n_in; (void)out_size; (void)ws_size;
  const int*   hpn_idx      = (const int*)d_in[0];
  const int*   nuc_idx      = (const int*)d_in[1];
  const float* h_nei        = (const float*)d_in[2];
  const float* graph_latent = (const float*)d_in[3];
  const float* Wz_mp=(const float*)d_in[4];  const float* bz_mp=(const float*)d_in[5];
  const float* Wr_mp=(const float*)d_in[6];  const float* br_mp=(const float*)d_in[7];
  const float* Ur_mp=(const float*)d_in[8];
  const float* Wh_mp=(const float*)d_in[9];  const float* bh_mp=(const float*)d_in[10];
  const float* Wz_nuc=(const float*)d_in[11]; const float* bz_nuc=(const float*)d_in[12];
  const float* Wr_nuc=(const float*)d_in[13]; const float* br_nuc=(const float*)d_in[14];
  const float* Wh_nuc=(const float*)d_in[15]; const float* bh_nuc=(const float*)d_in[16];
  const float* W_hpn_nl=(const float*)d_in[17]; const float* b_hpn_nl=(const float*)d_in[18];
  const float* W_hpn=(const float*)d_in[19];  const float* b_hpn=(const float*)d_in[20];
  const float* W_nuc_nl=(const float*)d_in[21]; const float* b_nuc_nl=(const float*)d_in[22];
  const float* W_nuc=(const float*)d_in[23];  const float* b_nuc=(const float*)d_in[24];
  const float* W_topo_nl=(const float*)d_in[25]; const float* b_topo_nl=(const float*)d_in[26];
  const float* W_topo=(const float*)d_in[27]; const float* b_topo=(const float*)d_in[28];

  float* ws = (float*)d_ws;
  size_t off = 0;
  auto take = [&](size_t nfl){ float* p = ws + off; off += nfl; return p; };
  // graphgru fp32 transposed weights
  float* wt_z_mp   = take((size_t)HD*HD);
  float* wt_ur     = take((size_t)HD*HD);
  float* wt_h_mp   = take((size_t)HD*HD);
  float* wt_topo   = take((size_t)HD*HD);
  float* wt_nl_lat = take((size_t)LATD*HD);
  float* wx_z_mp   = take((size_t)NHPN*HD);
  float* wx_h_mp   = take((size_t)NHPN*HD);
  float* wx_r_mp   = take((size_t)NHPN*HD);
  // scan bf16 fragment weights
  short* fz   = (short*)take((size_t)HD*HD/2);
  short* fr   = (short*)take((size_t)HD*HD/2);
  short* fh   = (short*)take((size_t)HD*HD/2);
  short* fnuc = (short*)take((size_t)HD*HD/2);
  short* fhpn = (short*)take((size_t)HD*HD/2);
  float* wxbz = take((size_t)NNUC*HD);
  float* wxbr = take((size_t)NNUC*HD);
  float* wxbh = take((size_t)NNUC*HD);
  float* latp = take((size_t)NROWS*HD);
  float* hF   = take((size_t)NROWS*HD);            // doubles as msg
  short* hB   = (short*)take((size_t)NROWS*HD/2);
  short* ghB  = (short*)take((size_t)NROWS*HD/2);
  float* zF   = take((size_t)NROWS*HD);
  float* nucp = take((size_t)8*NROWS*NNUC);
  float* nucpH= take((size_t)16*NROWS*NNUC);
  float* hpnp = take((size_t)16*NROWS*NHPN);

  float* out       = (float*)d_out;
  float* out_newh  = out;
  float* out_hpn   = out + (size_t)NROWS*HD;
  float* out_nuc   = out_hpn + (size_t)NROWS*NHPN;
  float* out_stop  = out_nuc + (size_t)NROWS*LSEQ*NNUC;

  auto T = [&](const float* src, float* dst, int sc, int coff, int nh){
    int total = nh*HD;
    transpose_w<<<(total+255)/256, 256, 0, stream_>>>(src, dst, sc, coff, nh);
  };
  T(Wz_mp,    wt_z_mp,   HD+NHPN, NHPN, HD);
  T(Wz_mp,    wx_z_mp,   HD+NHPN, 0,    NHPN);
  T(Wr_mp,    wx_r_mp,   NHPN,    0,    NHPN);
  T(Ur_mp,    wt_ur,     HD,      0,    HD);
  T(Wh_mp,    wt_h_mp,   HD+NHPN, NHPN, HD);
  T(Wh_mp,    wx_h_mp,   HD+NHPN, 0,    NHPN);
  T(W_topo_nl,wt_topo,   HD,      0,    HD);
  T(W_nuc_nl, wt_nl_lat, HD+LATD, HD,   LATD);

  const int FB = (HD*HD+255)/256;
  fragprep_k<<<FB,256,0,stream_>>>(Wz_nuc,   fz,   HD+NNUC, NNUC);
  fragprep_k<<<FB,256,0,stream_>>>(Wr_nuc,   fr,   HD+NNUC, NNUC);
  fragprep_k<<<FB,256,0,stream_>>>(Wh_nuc,   fh,   HD+NNUC, NNUC);
  fragprep_k<<<FB,256,0,stream_>>>(W_nuc_nl, fnuc, HD+LATD, 0);
  fragprep_k<<<FB,256,0,stream_>>>(W_hpn_nl, fhpn, HD,      0);

  const int WB = (NNUC*HD+255)/256;
  wxbprep_k<<<WB,256,0,stream_>>>(Wz_nuc, bz_nuc, wxbz, HD+NNUC);
  wxbprep_k<<<WB,256,0,stream_>>>(Wr_nuc, br_nuc, wxbr, HD+NNUC);
  wxbprep_k<<<WB,256,0,stream_>>>(Wh_nuc, bh_nuc, wxbh, HD+NNUC);

  latp_k<<<NROWS/16, 512, 0, stream_>>>(graph_latent, wt_nl_lat, b_nuc_nl, latp);

  graphgru_k<<<NROWS/8, 512, 0, stream_>>>(
      hpn_idx, h_nei,
      wt_z_mp, wx_z_mp, bz_mp,
      wx_r_mp, br_mp, wt_ur,
      wt_h_mp, wx_h_mp, bh_mp,
      wt_topo, b_topo_nl, W_topo, b_topo,
      hF, out_stop);

  bf16cast_k<<<(NROWS*HD)/256, 256, 0, stream_>>>(hF, hB);

  for (int t = 0; t < LSEQ; ++t){
    zrnuc_k<<<dim3(32,12), 512, 0, stream_>>>(
        t, nuc_idx, fz, fr, fnuc, hB, hF,
        wxbz, wxbr, latp, W_nuc, zF, ghB, nucp);
    cand_k<<<dim3(64,4), 512, 0, stream_>>>(
        t, nuc_idx, fh, ghB, wxbh, zF, hF, hB,
        nucp, b_nuc, out_nuc);
  }

  heads_k<<<dim3(64,8), 512, 0, stream_>>>(
      fnuc, fhpn, hB, latp, W_nuc, b_hpn_nl, W_hpn, nucpH, hpnp);
  final_red_k<<<128, 256, 0, stream_>>>(
      nucpH, hpnp, b_nuc, b_hpn, hF, out_newh, out_hpn, out_nuc);
}

// Round 9
// 2342.024 us; speedup vs baseline: 2.7539x; 1.0591x over previous
//
#include <hip/hip_runtime.h>
#include <math.h>

#define NROWS 2048
#define KNEI  8
#define LSEQ  64
#define HD    512
#define HD4   128
#define LATD  128
#define NHPN  4
#define NNUC  5

typedef __attribute__((ext_vector_type(8))) short s8b;   // 8 bf16 (16B)
typedef __attribute__((ext_vector_type(4))) float f4;    // MFMA acc

#define MFMA16(a,b,c) __builtin_amdgcn_mfma_f32_16x16x32_bf16(a,b,c,0,0,0)

__device__ __forceinline__ f4 f4zero(){ f4 z; z[0]=0.f; z[1]=0.f; z[2]=0.f; z[3]=0.f; return z; }
__device__ __forceinline__ float sigf(float x){ return __fdividef(1.0f, 1.0f + __expf(-x)); }
__device__ __forceinline__ float tanhf_fast(float x){
  float e = __expf(-2.0f*fabsf(x));
  float t = __fdividef(1.0f - e, 1.0f + e);
  return x >= 0.f ? t : -t;
}
__device__ __forceinline__ unsigned short f2bf(float x){
  union{float f; unsigned u;} v; v.f = x;
  unsigned r = (v.u + 0x7FFFu + ((v.u>>16)&1u)) >> 16;
  return (unsigned short)r;
}

__device__ __forceinline__ void dma16(const short* g, const short* l){
  __builtin_amdgcn_global_load_lds(
      (const __attribute__((address_space(1))) void*)(unsigned long long)g,
      (__attribute__((address_space(3))) void*)(unsigned long long)l,
      16, 0, 0);
}

// ----- fp32 helpers for graphgru -----
__device__ __forceinline__ void fma4(float4& a, float s, float4 w){
  a.x = fmaf(s,w.x,a.x); a.y = fmaf(s,w.y,a.y); a.z = fmaf(s,w.z,a.z); a.w = fmaf(s,w.w,a.w);
}
__device__ __forceinline__ void add4(float4& a, float4 b){ a.x+=b.x; a.y+=b.y; a.z+=b.z; a.w+=b.w; }
__device__ __forceinline__ float4 sig4(float4 v){
  return make_float4(1.f/(1.f+__expf(-v.x)),1.f/(1.f+__expf(-v.y)),1.f/(1.f+__expf(-v.z)),1.f/(1.f+__expf(-v.w)));
}
__device__ __forceinline__ float4 relu4(float4 v){ return make_float4(fmaxf(v.x,0.f),fmaxf(v.y,0.f),fmaxf(v.z,0.f),fmaxf(v.w,0.f)); }
__device__ __forceinline__ float dot4(float4 a, float4 b){ return a.x*b.x + a.y*b.y + a.z*b.z + a.w*b.w; }
__device__ __forceinline__ float4 gate_mul(float4 tv, float4 e){
  return make_float4((1.f/(1.f+__expf(-tv.x)))*e.x,(1.f/(1.f+__expf(-tv.y)))*e.y,
                     (1.f/(1.f+__expf(-tv.z)))*e.z,(1.f/(1.f+__expf(-tv.w)))*e.w);
}
__device__ __forceinline__ float4 gru_out(float4 z, float4 hprev, float4 pre){
  return make_float4((1.f-z.x)*hprev.x + z.x*tanhf(pre.x),
                     (1.f-z.y)*hprev.y + z.y*tanhf(pre.y),
                     (1.f-z.z)*hprev.z + z.z*tanhf(pre.z),
                     (1.f-z.w)*hprev.w + z.w*tanhf(pre.w));
}

// ---------------- prep kernels ----------------

__global__ void transpose_w(const float* __restrict__ src, float* __restrict__ dst,
                            int src_cols, int col_off, int nh){
  int idx = blockIdx.x*256 + threadIdx.x;
  if (idx >= nh*HD) return;
  int h = idx / HD, o = idx - h*HD;
  dst[idx] = src[o*src_cols + col_off + h];
}

// B-frag layout (per 16x16x32 tile, 1KB): dst[tile*512 + l*8 + j] = W[n][k]
__global__ void fragprep_k(const float* __restrict__ W, short* __restrict__ dst,
                           int src_cols, int col_off){
  int idx = blockIdx.x*256 + threadIdx.x;
  if (idx >= HD*HD) return;
  int j = idx&7, l = (idx>>3)&63, tile = idx>>9;
  int kc = tile&15, ot = tile>>4;
  int row = ot*16 + (l&15), k = kc*32 + (l>>4)*8 + j;
  dst[idx] = (short)f2bf(W[(size_t)row*src_cols + col_off + k]);
}

// wxb[c*HD + n] = W[n][c] + b[n]
__global__ void wxbprep_k(const float* __restrict__ W, const float* __restrict__ b,
                          float* __restrict__ dst, int src_cols){
  int idx = blockIdx.x*256 + threadIdx.x;
  if (idx >= NNUC*HD) return;
  int c = idx/HD, n = idx - c*HD;
  dst[idx] = W[(size_t)n*src_cols + c] + b[n];
}

__global__ void bf16cast_k(const float* __restrict__ src, short* __restrict__ dst){
  int i = blockIdx.x*256 + threadIdx.x;
  dst[i] = (short)f2bf(src[i]);
}

// latp[n][o] = b_nl[o] + sum_q gl[n][q]*wtlat[q*HD+o]
__global__ __launch_bounds__(512) void latp_k(const float* __restrict__ gl, const float* __restrict__ wtlat,
                     const float* __restrict__ bnl, float* __restrict__ latp){
  __shared__ float gls[16][LATD];
  int b = blockIdx.x, t = threadIdx.x;
  for (int i=t;i<16*LATD;i+=512) gls[i/LATD][i%LATD] = gl[(size_t)(b*16)*LATD + i];
  __syncthreads();
  float acc[16];
  float bv = bnl[t];
  #pragma unroll
  for (int r=0;r<16;++r) acc[r]=bv;
  for (int q=0;q<LATD;++q){
    float wv = wtlat[(size_t)q*HD + t];
    #pragma unroll
    for (int r=0;r<16;++r) acc[r] = fmaf(gls[r][q], wv, acc[r]);
  }
  #pragma unroll
  for (int r=0;r<16;++r) latp[(size_t)(b*16+r)*HD + t] = acc[r];
}

// ---------------- GraphGRU (unchanged verified fp32 path) ----------------
__global__ __launch_bounds__(512) void graphgru_k(
    const int* __restrict__ hpn_idx, const float* __restrict__ h_nei,
    const float* __restrict__ wt_z, const float* __restrict__ wx_z, const float* __restrict__ bz,
    const float* __restrict__ wx_r, const float* __restrict__ br,
    const float* __restrict__ wt_ur,
    const float* __restrict__ wt_h, const float* __restrict__ wx_h, const float* __restrict__ bh,
    const float* __restrict__ wt_topo, const float* __restrict__ b_topo_nl,
    const float* __restrict__ w_topo, const float* __restrict__ b_topo,
    float* __restrict__ msg, float* __restrict__ out_stop)
{
  __shared__ float sumh[8][HD];
  __shared__ float hk[8][HD];
  __shared__ float sg[8][HD];
  __shared__ float red[8][2];
  const int t = threadIdx.x, lane = t&63, wv = t>>6;
  const int r0 = (wv>>1)<<1;
  const int oh = wv&1;
  const int ob4 = 64*oh + lane;
  const int n0 = blockIdx.x*8;
  float4* sumh4 = (float4*)(&sumh[0][0]);
  float4* hk4   = (float4*)(&hk[0][0]);
  float4* sg4   = (float4*)(&sg[0][0]);
  const float4* hn4 = (const float4*)h_nei;

  for (int idx=t; idx<8*HD4; idx+=512){
    int r = idx>>7, c = idx&127;
    size_t base = ((size_t)(n0+r))*KNEI*HD4 + c;
    float4 s = hn4[base];
    #pragma unroll
    for (int k=1;k<KNEI;++k) add4(s, hn4[base + (size_t)k*HD4]);
    sumh4[idx] = s;
  }
  __syncthreads();

  const int hp0 = hpn_idx[n0+r0], hp1 = hpn_idx[n0+r0+1];
  const float4* bz4 = (const float4*)bz;
  const float4* wxz4 = (const float4*)wx_z;
  const float4* wtz4 = (const float4*)wt_z;
  float4 z0 = bz4[ob4]; add4(z0, wxz4[hp0*HD4 + ob4]);
  float4 z1 = bz4[ob4]; add4(z1, wxz4[hp1*HD4 + ob4]);
  for (int h=0;h<HD;++h){
    float a0 = sumh[r0][h], a1 = sumh[r0+1][h];
    float4 w = wtz4[h*HD4 + ob4];
    fma4(z0,a0,w); fma4(z1,a1,w);
  }
  z0 = sig4(z0); z1 = sig4(z1);

  const float4* br4 = (const float4*)br;
  const float4* wxr4 = (const float4*)wx_r;
  const float4* wtur4 = (const float4*)wt_ur;
  float4 rb0 = br4[ob4]; add4(rb0, wxr4[hp0*HD4 + ob4]);
  float4 rb1 = br4[ob4]; add4(rb1, wxr4[hp1*HD4 + ob4]);
  float4 sg0 = make_float4(0.f,0.f,0.f,0.f), sg1 = sg0;
  for (int k=0;k<KNEI;++k){
    __syncthreads();
    for (int idx=t; idx<8*HD4; idx+=512){
      int r = idx>>7, c = idx&127;
      hk4[idx] = hn4[((size_t)(n0+r)*KNEI + (size_t)k)*HD4 + c];
    }
    __syncthreads();
    float4 t0 = rb0, t1 = rb1;
    for (int h=0;h<HD;++h){
      float a0 = hk[r0][h], a1 = hk[r0+1][h];
      float4 w = wtur4[h*HD4 + ob4];
      fma4(t0,a0,w); fma4(t1,a1,w);
    }
    float4 e0 = hk4[r0*HD4 + ob4], e1 = hk4[(r0+1)*HD4 + ob4];
    add4(sg0, gate_mul(t0, e0));
    add4(sg1, gate_mul(t1, e1));
  }
  __syncthreads();
  sg4[r0*HD4+ob4] = sg0; sg4[(r0+1)*HD4+ob4] = sg1;
  __syncthreads();

  const float4* bh4 = (const float4*)bh;
  const float4* wxh4 = (const float4*)wx_h;
  const float4* wth4 = (const float4*)wt_h;
  float4 p0 = bh4[ob4]; add4(p0, wxh4[hp0*HD4+ob4]);
  float4 p1 = bh4[ob4]; add4(p1, wxh4[hp1*HD4+ob4]);
  for (int h=0;h<HD;++h){
    float a0 = sg[r0][h], a1 = sg[r0+1][h];
    float4 w = wth4[h*HD4+ob4];
    fma4(p0,a0,w); fma4(p1,a1,w);
  }
  float4 sh0 = sumh4[r0*HD4+ob4], sh1 = sumh4[(r0+1)*HD4+ob4];
  float4 m0 = gru_out(z0, sh0, p0);
  float4 m1 = gru_out(z1, sh1, p1);
  ((float4*)msg)[(size_t)(n0+r0)*HD4 + ob4] = m0;
  ((float4*)msg)[(size_t)(n0+r0+1)*HD4 + ob4] = m1;
  __syncthreads();
  sg4[r0*HD4+ob4] = m0; sg4[(r0+1)*HD4+ob4] = m1;
  __syncthreads();

  const float4* btnl4 = (const float4*)b_topo_nl;
  const float4* wttopo4 = (const float4*)wt_topo;
  float4 q0 = btnl4[ob4], q1 = btnl4[ob4];
  for (int h=0;h<HD;++h){
    float a0 = sg[r0][h], a1 = sg[r0+1][h];
    float4 w = wttopo4[h*HD4+ob4];
    fma4(q0,a0,w); fma4(q1,a1,w);
  }
  float4 wt4v = ((const float4*)w_topo)[ob4];
  float th0 = dot4(relu4(q0), wt4v);
  float th1 = dot4(relu4(q1), wt4v);
  #pragma unroll
  for (int s=32;s>0;s>>=1){ th0 += __shfl_down(th0,s); th1 += __shfl_down(th1,s); }
  if (lane==0){ red[r0][oh]=th0; red[r0+1][oh]=th1; }
  __syncthreads();
  if (t<8) out_stop[n0+t] = red[t][0] + red[t][1] + b_topo[0];
}

// ---------------- scan step kernel A: z, r, nuc GEMMs on h(t) ----------------
// grid (32 row-tiles x 12 col-groups), 512 threads. cg>>2: 0=z,1=r,2=nuc.
// Full 128KB weight slice staged in 2 phases (2 latencies, phase-B hidden).
__global__ __launch_bounds__(512) void zrnuc_k(
    int t, const int* __restrict__ nuc_idx,
    const short* __restrict__ fz, const short* __restrict__ fr, const short* __restrict__ fnuc,
    const short* __restrict__ hB, const float* __restrict__ hF,
    const float* __restrict__ wxbz, const float* __restrict__ wxbr,
    const float* __restrict__ latp, const float* __restrict__ w_nuc,
    float* __restrict__ zF, short* __restrict__ ghB, float* __restrict__ nucp)
{
  const int cg = blockIdx.y;
  const int mat = cg>>2;
  if (t==0 && mat==2) return;        // no hs[-1]
  __shared__ __align__(16) short stage[16][4096];   // [kc][otile*512 + s] = 128KB
  __shared__ int codes_s[64];
  const int tt = threadIdx.x, l = tt&63, w = tt>>6, lm = l&15, g = l>>4;
  const int rt = blockIdx.x, row0 = rt*64;
  const short* frag = (mat==0)?fz:((mat==1)?fr:fnuc);
  const int otb = (cg&3)*8;
  if (tt<64) codes_s[tt] = nuc_idx[(size_t)(row0+tt)*LSEQ + t];
  const int mt = w>>1, nh2 = w&1;
  const short* gsrc = frag + ((size_t)(otb + w)*16)*512 + (size_t)l*8;
  // phase A issue: kc 0..7 (wave w stages its otile w)
  #pragma unroll
  for (int kc=0;kc<8;++kc) dma16(gsrc + (size_t)kc*512, &stage[kc][w*512 + l*8]);
  // preload 16 A-frags (overlaps DMA)
  s8b af[16];
  {
    const s8b* hrow = (const s8b*)(hB + (size_t)(row0 + mt*16 + lm)*HD);
    #pragma unroll
    for (int kc=0;kc<16;++kc) af[kc] = hrow[kc*4 + g];
  }
  asm volatile("s_waitcnt vmcnt(0)" ::: "memory");
  __syncthreads();
  // phase B issue: kc 8..15 (lands while we compute phase A)
  #pragma unroll
  for (int kc=8;kc<16;++kc) dma16(gsrc + (size_t)kc*512, &stage[kc][w*512 + l*8]);
  f4 acc[4];
  #pragma unroll
  for (int i=0;i<4;++i) acc[i]=f4zero();
  #pragma unroll
  for (int kc=0;kc<8;++kc){
    #pragma unroll
    for (int i=0;i<4;++i){
      s8b b = ((const s8b*)&stage[kc][(nh2*4+i)*512])[l];
      acc[i] = MFMA16(af[kc], b, acc[i]);
    }
  }
  asm volatile("s_waitcnt vmcnt(0)" ::: "memory");
  __syncthreads();
  #pragma unroll
  for (int kc=8;kc<16;++kc){
    #pragma unroll
    for (int i=0;i<4;++i){
      s8b b = ((const s8b*)&stage[kc][(nh2*4+i)*512])[l];
      acc[i] = MFMA16(af[kc], b, acc[i]);
    }
  }
  // epilogues (D: row=row0+mt*16+g*4+q, col=(cg&3)*128+(nh2*4+i)*16+lm)
  const int colb = (cg&3)*128;
  if (mat==0){
    #pragma unroll
    for (int i=0;i<4;++i){
      const int col = colb + (nh2*4+i)*16 + lm;
      #pragma unroll
      for (int q=0;q<4;++q){
        const int r = mt*16 + g*4 + q;
        float zv = sigf(acc[i][q] + wxbz[codes_s[r]*HD + col]);
        zF[(size_t)(row0+r)*HD + col] = zv;
      }
    }
  } else if (mat==1){
    #pragma unroll
    for (int i=0;i<4;++i){
      const int col = colb + (nh2*4+i)*16 + lm;
      #pragma unroll
      for (int q=0;q<4;++q){
        const int r = mt*16 + g*4 + q;
        float rv = sigf(acc[i][q] + wxbr[codes_s[r]*HD + col]);
        ghB[(size_t)(row0+r)*HD + col] = (short)f2bf(rv * hF[(size_t)(row0+r)*HD + col]);
      }
    }
  } else {
    float p[4][NNUC];
    #pragma unroll
    for (int q=0;q<4;++q)
      #pragma unroll
      for (int j=0;j<NNUC;++j) p[q][j]=0.f;
    #pragma unroll
    for (int i=0;i<4;++i){
      const int col = colb + (nh2*4+i)*16 + lm;
      #pragma unroll
      for (int q=0;q<4;++q){
        const int r = mt*16 + g*4 + q;
        float hid = fmaxf(acc[i][q] + latp[(size_t)(row0+r)*HD + col], 0.f);
        #pragma unroll
        for (int j=0;j<NNUC;++j) p[q][j] = fmaf(hid, w_nuc[(size_t)j*HD + col], p[q][j]);
      }
    }
    #pragma unroll
    for (int s=1;s<16;s<<=1)
      #pragma unroll
      for (int q=0;q<4;++q)
        #pragma unroll
        for (int j=0;j<NNUC;++j) p[q][j] += __shfl_xor(p[q][j], s);
    if (lm==0){
      const int slab = (cg&3)*2 + nh2;
      #pragma unroll
      for (int q=0;q<4;++q){
        const int row = row0 + mt*16 + g*4 + q;
        #pragma unroll
        for (int j=0;j<NNUC;++j)
          nucp[((size_t)slab*NROWS + row)*NNUC + j] = p[q][j];
      }
    }
  }
}

// ---------------- scan step kernel B: candidate GEMM + h update ----------------
// grid (64 row-tiles x 4 col-groups), 512 threads. Same 2-phase staging.
__global__ __launch_bounds__(512) void cand_k(
    int t, const int* __restrict__ nuc_idx,
    const short* __restrict__ fh,
    const short* __restrict__ ghB,
    const float* __restrict__ wxbh,
    const float* __restrict__ zF, float* __restrict__ hF, short* __restrict__ hB,
    const float* __restrict__ nucp, const float* __restrict__ b_nuc,
    float* __restrict__ out_nuc)
{
  __shared__ __align__(16) short stage[16][4096];
  __shared__ int codes_s[32];
  const int tt = threadIdx.x, l = tt&63, w = tt>>6, lm = l&15, g = l>>4;
  const int rt = blockIdx.x, row0 = rt*32, cg = blockIdx.y;
  if (tt<32) codes_s[tt] = nuc_idx[(size_t)(row0+tt)*LSEQ + t];
  const int mt = w>>2, ntp = w&3;
  const short* gsrc = fh + ((size_t)(cg*8 + w)*16)*512 + (size_t)l*8;
  #pragma unroll
  for (int kc=0;kc<8;++kc) dma16(gsrc + (size_t)kc*512, &stage[kc][w*512 + l*8]);
  s8b af[16];
  {
    const s8b* grow = (const s8b*)(ghB + (size_t)(row0 + mt*16 + lm)*HD);
    #pragma unroll
    for (int kc=0;kc<16;++kc) af[kc] = grow[kc*4 + g];
  }
  asm volatile("s_waitcnt vmcnt(0)" ::: "memory");
  __syncthreads();
  #pragma unroll
  for (int kc=8;kc<16;++kc) dma16(gsrc + (size_t)kc*512, &stage[kc][w*512 + l*8]);
  f4 acc[2]; acc[0]=f4zero(); acc[1]=f4zero();
  #pragma unroll
  for (int kc=0;kc<8;++kc){
    #pragma unroll
    for (int i2=0;i2<2;++i2){
      s8b b = ((const s8b*)&stage[kc][(ntp*2+i2)*512])[l];
      acc[i2] = MFMA16(af[kc], b, acc[i2]);
    }
  }
  asm volatile("s_waitcnt vmcnt(0)" ::: "memory");
  __syncthreads();
  #pragma unroll
  for (int kc=8;kc<16;++kc){
    #pragma unroll
    for (int i2=0;i2<2;++i2){
      s8b b = ((const s8b*)&stage[kc][(ntp*2+i2)*512])[l];
      acc[i2] = MFMA16(af[kc], b, acc[i2]);
    }
  }
  #pragma unroll
  for (int i2=0;i2<2;++i2){
    const int col = cg*128 + (ntp*2+i2)*16 + lm;
    #pragma unroll
    for (int q=0;q<4;++q){
      const int r = mt*16 + g*4 + q;
      const size_t idx = (size_t)(row0+r)*HD + col;
      float pre = tanhf_fast(acc[i2][q] + wxbh[codes_s[r]*HD + col]);
      float zv = zF[idx];
      float hn = (1.f - zv)*hF[idx] + zv*pre;
      hF[idx] = hn;
      hB[idx] = (short)f2bf(hn);
    }
  }
  // reduce nuc partials for l = t-1 (written by zrnuc_k(t))
  if (t > 0 && cg == 0 && tt < 32*NNUC){
    int rr = tt/NNUC, j = tt - rr*NNUC;
    int row = row0 + rr;
    float s2 = b_nuc[j];
    #pragma unroll
    for (int s8=0;s8<8;++s8) s2 += nucp[((size_t)s8*NROWS + row)*NNUC + j];
    out_nuc[((size_t)row*LSEQ + (t-1))*NNUC + j] = s2;
  }
}

// ---------------- tail heads: nuc(l=63) + hpn on h(64) ----------------
// grid (64 row-tiles x 8): cg>>2: 0=nuc, 1=hpn; cols (cg&3)*128.
__global__ __launch_bounds__(512) void heads_k(
    const short* __restrict__ fnuc, const short* __restrict__ fhpn,
    const short* __restrict__ hB,
    const float* __restrict__ latp, const float* __restrict__ w_nuc,
    const float* __restrict__ b_hpn_nl, const float* __restrict__ w_hpn,
    float* __restrict__ nucpH, float* __restrict__ hpnp)
{
  __shared__ __align__(16) short stage[16][4096];
  const int tt = threadIdx.x, l = tt&63, w = tt>>6, lm = l&15, g = l>>4;
  const int rt = blockIdx.x, row0 = rt*32, cg = blockIdx.y;
  const int mat = cg>>2;
  const short* frag = mat ? fhpn : fnuc;
  const int mt = w>>2, ntp = w&3;
  const short* gsrc = frag + ((size_t)((cg&3)*8 + w)*16)*512 + (size_t)l*8;
  #pragma unroll
  for (int kc=0;kc<8;++kc) dma16(gsrc + (size_t)kc*512, &stage[kc][w*512 + l*8]);
  s8b af[16];
  {
    const s8b* hrow = (const s8b*)(hB + (size_t)(row0 + mt*16 + lm)*HD);
    #pragma unroll
    for (int kc=0;kc<16;++kc) af[kc] = hrow[kc*4 + g];
  }
  asm volatile("s_waitcnt vmcnt(0)" ::: "memory");
  __syncthreads();
  #pragma unroll
  for (int kc=8;kc<16;++kc) dma16(gsrc + (size_t)kc*512, &stage[kc][w*512 + l*8]);
  f4 acc[2]; acc[0]=f4zero(); acc[1]=f4zero();
  #pragma unroll
  for (int kc=0;kc<8;++kc){
    #pragma unroll
    for (int i2=0;i2<2;++i2){
      s8b b = ((const s8b*)&stage[kc][(ntp*2+i2)*512])[l];
      acc[i2] = MFMA16(af[kc], b, acc[i2]);
    }
  }
  asm volatile("s_waitcnt vmcnt(0)" ::: "memory");
  __syncthreads();
  #pragma unroll
  for (int kc=8;kc<16;++kc){
    #pragma unroll
    for (int i2=0;i2<2;++i2){
      s8b b = ((const s8b*)&stage[kc][(ntp*2+i2)*512])[l];
      acc[i2] = MFMA16(af[kc], b, acc[i2]);
    }
  }
  const int slab = (cg&3)*4 + ntp;
  if (mat==0){
    float p[4][NNUC];
    #pragma unroll
    for (int q=0;q<4;++q)
      #pragma unroll
      for (int j=0;j<NNUC;++j) p[q][j]=0.f;
    #pragma unroll
    for (int i2=0;i2<2;++i2){
      const int col = (cg&3)*128 + (ntp*2+i2)*16 + lm;
      #pragma unroll
      for (int q=0;q<4;++q){
        const int r = mt*16 + g*4 + q;
        float hid = fmaxf(acc[i2][q] + latp[(size_t)(row0+r)*HD + col], 0.f);
        #pragma unroll
        for (int j=0;j<NNUC;++j) p[q][j] = fmaf(hid, w_nuc[(size_t)j*HD + col], p[q][j]);
      }
    }
    #pragma unroll
    for (int s=1;s<16;s<<=1)
      #pragma unroll
      for (int q=0;q<4;++q)
        #pragma unroll
        for (int j=0;j<NNUC;++j) p[q][j] += __shfl_xor(p[q][j], s);
    if (lm==0){
      #pragma unroll
      for (int q=0;q<4;++q){
        const int row = row0 + mt*16 + g*4 + q;
        #pragma unroll
        for (int j=0;j<NNUC;++j)
          nucpH[((size_t)slab*NROWS + row)*NNUC + j] = p[q][j];
      }
    }
  } else {
    float p[4][NHPN];
    #pragma unroll
    for (int q=0;q<4;++q)
      #pragma unroll
      for (int j=0;j<NHPN;++j) p[q][j]=0.f;
    #pragma unroll
    for (int i2=0;i2<2;++i2){
      const int col = (cg&3)*128 + (ntp*2+i2)*16 + lm;
      float bnl = b_hpn_nl[col];
      #pragma unroll
      for (int q=0;q<4;++q){
        float hid = fmaxf(acc[i2][q] + bnl, 0.f);
        #pragma unroll
        for (int j=0;j<NHPN;++j) p[q][j] = fmaf(hid, w_hpn[(size_t)j*HD + col], p[q][j]);
      }
    }
    #pragma unroll
    for (int s=1;s<16;s<<=1)
      #pragma unroll
      for (int q=0;q<4;++q)
        #pragma unroll
        for (int j=0;j<NHPN;++j) p[q][j] += __shfl_xor(p[q][j], s);
    if (lm==0){
      #pragma unroll
      for (int q=0;q<4;++q){
        const int row = row0 + mt*16 + g*4 + q;
        #pragma unroll
        for (int j=0;j<NHPN;++j)
          hpnp[((size_t)slab*NROWS + row)*NHPN + j] = p[q][j];
      }
    }
  }
}

__global__ void final_red_k(const float* __restrict__ nucpH, const float* __restrict__ hpnp,
    const float* __restrict__ b_nuc, const float* __restrict__ b_hpn,
    const float* __restrict__ hF,
    float* __restrict__ out_newh, float* __restrict__ out_hpn, float* __restrict__ out_nuc)
{
  int gid = blockIdx.x*256 + threadIdx.x;   // grid 128x256 = 32768
  if (gid < NROWS*NNUC){
    int n = gid/NNUC, j = gid - n*NNUC;
    float s = b_nuc[j];
    #pragma unroll
    for (int s8=0;s8<16;++s8) s += nucpH[((size_t)s8*NROWS + n)*NNUC + j];
    out_nuc[((size_t)n*LSEQ + 63)*NNUC + j] = s;
  } else if (gid < NROWS*NNUC + NROWS*NHPN){
    int g2 = gid - NROWS*NNUC;
    int n = g2/NHPN, j = g2 - n*NHPN;
    float s = b_hpn[j];
    #pragma unroll
    for (int s8=0;s8<16;++s8) s += hpnp[((size_t)s8*NROWS + n)*NHPN + j];
    out_hpn[(size_t)n*NHPN + j] = s;
  }
  const float4* src = (const float4*)hF;
  float4* dst = (float4*)out_newh;
  for (int i = gid; i < NROWS*HD/4; i += 32768) dst[i] = src[i];
}

// ---------------- host ----------------
extern "C" void kernel_launch(void* const* d_in, const int* in_sizes, int n_in,
                              void* d_out, int out_size, void* d_ws, size_t ws_size,
                              hipStream_t stream_){
  (void)in_sizes; (void)n_in; (void)out_size; (void)ws_size;
  const int*   hpn_idx      = (const int*)d_in[0];
  const int*   nuc_idx      = (const int*)d_in[1];
  const float* h_nei        = (const float*)d_in[2];
  const float* graph_latent = (const float*)d_in[3];
  const float* Wz_mp=(const float*)d_in[4];  const float* bz_mp=(const float*)d_in[5];
  const float* Wr_mp=(const float*)d_in[6];  const float* br_mp=(const float*)d_in[7];
  const float* Ur_mp=(const float*)d_in[8];
  const float* Wh_mp=(const float*)d_in[9];  const float* bh_mp=(const float*)d_in[10];
  const float* Wz_nuc=(const float*)d_in[11]; const float* bz_nuc=(const float*)d_in[12];
  const float* Wr_nuc=(const float*)d_in[13]; const float* br_nuc=(const float*)d_in[14];
  const float* Wh_nuc=(const float*)d_in[15]; const float* bh_nuc=(const float*)d_in[16];
  const float* W_hpn_nl=(const float*)d_in[17]; const float* b_hpn_nl=(const float*)d_in[18];
  const float* W_hpn=(const float*)d_in[19];  const float* b_hpn=(const float*)d_in[20];
  const float* W_nuc_nl=(const float*)d_in[21]; const float* b_nuc_nl=(const float*)d_in[22];
  const float* W_nuc=(const float*)d_in[23];  const float* b_nuc=(const float*)d_in[24];
  const float* W_topo_nl=(const float*)d_in[25]; const float* b_topo_nl=(const float*)d_in[26];
  const float* W_topo=(const float*)d_in[27]; const float* b_topo=(const float*)d_in[28];

  float* ws = (float*)d_ws;
  size_t off = 0;
  auto take = [&](size_t nfl){ float* p = ws + off; off += nfl; return p; };
  // graphgru fp32 transposed weights
  float* wt_z_mp   = take((size_t)HD*HD);
  float* wt_ur     = take((size_t)HD*HD);
  float* wt_h_mp   = take((size_t)HD*HD);
  float* wt_topo   = take((size_t)HD*HD);
  float* wt_nl_lat = take((size_t)LATD*HD);
  float* wx_z_mp   = take((size_t)NHPN*HD);
  float* wx_h_mp   = take((size_t)NHPN*HD);
  float* wx_r_mp   = take((size_t)NHPN*HD);
  // scan bf16 fragment weights
  short* fz   = (short*)take((size_t)HD*HD/2);
  short* fr   = (short*)take((size_t)HD*HD/2);
  short* fh   = (short*)take((size_t)HD*HD/2);
  short* fnuc = (short*)take((size_t)HD*HD/2);
  short* fhpn = (short*)take((size_t)HD*HD/2);
  float* wxbz = take((size_t)NNUC*HD);
  float* wxbr = take((size_t)NNUC*HD);
  float* wxbh = take((size_t)NNUC*HD);
  float* latp = take((size_t)NROWS*HD);
  float* hF   = take((size_t)NROWS*HD);            // doubles as msg
  short* hB   = (short*)take((size_t)NROWS*HD/2);
  short* ghB  = (short*)take((size_t)NROWS*HD/2);
  float* zF   = take((size_t)NROWS*HD);
  float* nucp = take((size_t)8*NROWS*NNUC);
  float* nucpH= take((size_t)16*NROWS*NNUC);
  float* hpnp = take((size_t)16*NROWS*NHPN);

  float* out       = (float*)d_out;
  float* out_newh  = out;
  float* out_hpn   = out + (size_t)NROWS*HD;
  float* out_nuc   = out_hpn + (size_t)NROWS*NHPN;
  float* out_stop  = out_nuc + (size_t)NROWS*LSEQ*NNUC;

  auto T = [&](const float* src, float* dst, int sc, int coff, int nh){
    int total = nh*HD;
    transpose_w<<<(total+255)/256, 256, 0, stream_>>>(src, dst, sc, coff, nh);
  };
  T(Wz_mp,    wt_z_mp,   HD+NHPN, NHPN, HD);
  T(Wz_mp,    wx_z_mp,   HD+NHPN, 0,    NHPN);
  T(Wr_mp,    wx_r_mp,   NHPN,    0,    NHPN);
  T(Ur_mp,    wt_ur,     HD,      0,    HD);
  T(Wh_mp,    wt_h_mp,   HD+NHPN, NHPN, HD);
  T(Wh_mp,    wx_h_mp,   HD+NHPN, 0,    NHPN);
  T(W_topo_nl,wt_topo,   HD,      0,    HD);
  T(W_nuc_nl, wt_nl_lat, HD+LATD, HD,   LATD);

  const int FB = (HD*HD+255)/256;
  fragprep_k<<<FB,256,0,stream_>>>(Wz_nuc,   fz,   HD+NNUC, NNUC);
  fragprep_k<<<FB,256,0,stream_>>>(Wr_nuc,   fr,   HD+NNUC, NNUC);
  fragprep_k<<<FB,256,0,stream_>>>(Wh_nuc,   fh,   HD+NNUC, NNUC);
  fragprep_k<<<FB,256,0,stream_>>>(W_nuc_nl, fnuc, HD+LATD, 0);
  fragprep_k<<<FB,256,0,stream_>>>(W_hpn_nl, fhpn, HD,      0);

  const int WB = (NNUC*HD+255)/256;
  wxbprep_k<<<WB,256,0,stream_>>>(Wz_nuc, bz_nuc, wxbz, HD+NNUC);
  wxbprep_k<<<WB,256,0,stream_>>>(Wr_nuc, br_nuc, wxbr, HD+NNUC);
  wxbprep_k<<<WB,256,0,stream_>>>(Wh_nuc, bh_nuc, wxbh, HD+NNUC);

  latp_k<<<NROWS/16, 512, 0, stream_>>>(graph_latent, wt_nl_lat, b_nuc_nl, latp);

  graphgru_k<<<NROWS/8, 512, 0, stream_>>>(
      hpn_idx, h_nei,
      wt_z_mp, wx_z_mp, bz_mp,
      wx_r_mp, br_mp, wt_ur,
      wt_h_mp, wx_h_mp, bh_mp,
      wt_topo, b_topo_nl, W_topo, b_topo,
      hF, out_stop);

  bf16cast_k<<<(NROWS*HD)/256, 256, 0, stream_>>>(hF, hB);

  for (int t = 0; t < LSEQ; ++t){
    zrnuc_k<<<dim3(32,12), 512, 0, stream_>>>(
        t, nuc_idx, fz, fr, fnuc, hB, hF,
        wxbz, wxbr, latp, W_nuc, zF, ghB, nucp);
    cand_k<<<dim3(64,4), 512, 0, stream_>>>(
        t, nuc_idx, fh, ghB, wxbh, zF, hF, hB,
        nucp, b_nuc, out_nuc);
  }

  heads_k<<<dim3(64,8), 512, 0, stream_>>>(
      fnuc, fhpn, hB, latp, W_nuc, b_hpn_nl, W_hpn, nucpH, hpnp);
  final_red_k<<<128, 256, 0, stream_>>>(
      nucpH, hpnp, b_nuc, b_hpn, hF, out_newh, out_hpn, out_nuc);
}

// Round 10
// 2132.210 us; speedup vs baseline: 3.0249x; 1.0984x over previous
//
#include <hip/hip_runtime.h>
#include <math.h>

#define NROWS 2048
#define KNEI  8
#define LSEQ  64
#define HD    512
#define HD4   128
#define LATD  128
#define NHPN  4
#define NNUC  5

typedef __attribute__((ext_vector_type(8))) short s8b;   // 8 bf16 (16B)
typedef __attribute__((ext_vector_type(4))) short s4b;   // 4 bf16 (8B)
typedef __attribute__((ext_vector_type(4))) float f4;    // MFMA acc

#define MFMA16(a,b,c) __builtin_amdgcn_mfma_f32_16x16x32_bf16(a,b,c,0,0,0)

__device__ __forceinline__ f4 f4zero(){ f4 z; z[0]=0.f; z[1]=0.f; z[2]=0.f; z[3]=0.f; return z; }
__device__ __forceinline__ float sigf(float x){ return __fdividef(1.0f, 1.0f + __expf(-x)); }
__device__ __forceinline__ float tanhf_fast(float x){
  float e = __expf(-2.0f*fabsf(x));
  float t = __fdividef(1.0f - e, 1.0f + e);
  return x >= 0.f ? t : -t;
}
__device__ __forceinline__ unsigned short f2bf(float x){
  union{float f; unsigned u;} v; v.f = x;
  unsigned r = (v.u + 0x7FFFu + ((v.u>>16)&1u)) >> 16;
  return (unsigned short)r;
}
__device__ __forceinline__ void add4(float4& a, float4 b){ a.x+=b.x; a.y+=b.y; a.z+=b.z; a.w+=b.w; }

__device__ __forceinline__ void dma16(const short* g, const short* l){
  __builtin_amdgcn_global_load_lds(
      (const __attribute__((address_space(1))) void*)(unsigned long long)g,
      (__attribute__((address_space(3))) void*)(unsigned long long)l,
      16, 0, 0);
}

// ---------------- prep kernels ----------------

__global__ void transpose_w(const float* __restrict__ src, float* __restrict__ dst,
                            int src_cols, int col_off, int nh){
  int idx = blockIdx.x*256 + threadIdx.x;
  if (idx >= nh*HD) return;
  int h = idx / HD, o = idx - h*HD;
  dst[idx] = src[o*src_cols + col_off + h];
}

// B-frag layout (per 16x16x32 tile, 1KB): dst[tile*512 + l*8 + j] = W[n][k]
__global__ void fragprep_k(const float* __restrict__ W, short* __restrict__ dst,
                           int src_cols, int col_off){
  int idx = blockIdx.x*256 + threadIdx.x;
  if (idx >= HD*HD) return;
  int j = idx&7, l = (idx>>3)&63, tile = idx>>9;
  int kc = tile&15, ot = tile>>4;
  int row = ot*16 + (l&15), k = kc*32 + (l>>4)*8 + j;
  dst[idx] = (short)f2bf(W[(size_t)row*src_cols + col_off + k]);
}

// wxb[c*HD + n] = W[n][c] + b[n]   (nc codes)
__global__ void wxbprep2_k(const float* __restrict__ W, const float* __restrict__ b,
                           float* __restrict__ dst, int src_cols, int nc){
  int idx = blockIdx.x*256 + threadIdx.x;
  if (idx >= nc*HD) return;
  int c = idx/HD, n = idx - c*HD;
  dst[idx] = W[(size_t)n*src_cols + c] + b[n];
}

// latp[n][o] = b_nl[o] + sum_q gl[n][q]*wtlat[q*HD+o]
__global__ __launch_bounds__(512) void latp_k(const float* __restrict__ gl, const float* __restrict__ wtlat,
                     const float* __restrict__ bnl, float* __restrict__ latp){
  __shared__ float gls[16][LATD];
  int b = blockIdx.x, t = threadIdx.x;
  for (int i=t;i<16*LATD;i+=512) gls[i/LATD][i%LATD] = gl[(size_t)(b*16)*LATD + i];
  __syncthreads();
  float acc[16];
  float bv = bnl[t];
  #pragma unroll
  for (int r=0;r<16;++r) acc[r]=bv;
  for (int q=0;q<LATD;++q){
    float wv = wtlat[(size_t)q*HD + t];
    #pragma unroll
    for (int r=0;r<16;++r) acc[r] = fmaf(gls[r][q], wv, acc[r]);
  }
  #pragma unroll
  for (int r=0;r<16;++r) latp[(size_t)(b*16+r)*HD + t] = acc[r];
}

// sumh = h_nei.sum(k) fp32 + bf16 copy.  grid 512 x 512 (2048 rows x 128 f4-cols)
__global__ void sumcast_k(const float* __restrict__ h_nei,
                          float* __restrict__ sumhF, short* __restrict__ sumhB){
  int idx = blockIdx.x*512 + threadIdx.x;
  int n = idx >> 7, c4 = idx & 127;
  const float4* hn4 = (const float4*)h_nei;
  size_t base = (size_t)n*KNEI*HD4 + c4;
  float4 s = hn4[base];
  #pragma unroll
  for (int k=1;k<KNEI;++k) add4(s, hn4[base + (size_t)k*HD4]);
  ((float4*)sumhF)[(size_t)n*HD4 + c4] = s;
  s4b p;
  p[0]=(short)f2bf(s.x); p[1]=(short)f2bf(s.y); p[2]=(short)f2bf(s.z); p[3]=(short)f2bf(s.w);
  ((s4b*)sumhB)[(size_t)n*HD4 + c4] = p;
}

// ---------------- GraphGRU MFMA GEMMs ----------------
// Shared core (cand_k pattern): grid (64 row-tiles x 4 cg), 512 thr, 32 rows,
// 128 cols per block. mode: 0 = z gate, 1 = candidate+msg, 2 = topo head.
__global__ __launch_bounds__(512) void ggru_gemm_k(
    int mode,
    const short* __restrict__ frag,
    const short* __restrict__ A,
    const int* __restrict__ hpn_idx,
    const float* __restrict__ bias_tab,
    const float* __restrict__ sumhF, const float* __restrict__ zF_in,
    const float* __restrict__ w_topo,
    float* __restrict__ zF_out,
    float* __restrict__ hF, short* __restrict__ hB,
    float* __restrict__ topo_p)
{
  __shared__ __align__(16) short stage[16][4096];
  __shared__ int codes_s[32];
  const int tt = threadIdx.x, l = tt&63, w = tt>>6, lm = l&15, g = l>>4;
  const int rt = blockIdx.x, row0 = rt*32, cg = blockIdx.y;
  if (tt<32) codes_s[tt] = hpn_idx[row0+tt];
  const int mt = w>>2, ntp = w&3;
  const short* gsrc = frag + ((size_t)(cg*8 + w)*16)*512 + (size_t)l*8;
  #pragma unroll
  for (int kc=0;kc<8;++kc) dma16(gsrc + (size_t)kc*512, &stage[kc][w*512 + l*8]);
  s8b af[16];
  {
    const s8b* arow = (const s8b*)(A + (size_t)(row0 + mt*16 + lm)*HD);
    #pragma unroll
    for (int kc=0;kc<16;++kc) af[kc] = arow[kc*4 + g];
  }
  asm volatile("s_waitcnt vmcnt(0)" ::: "memory");
  __syncthreads();
  #pragma unroll
  for (int kc=8;kc<16;++kc) dma16(gsrc + (size_t)kc*512, &stage[kc][w*512 + l*8]);
  f4 acc[2]; acc[0]=f4zero(); acc[1]=f4zero();
  #pragma unroll
  for (int kc=0;kc<8;++kc){
    #pragma unroll
    for (int i2=0;i2<2;++i2){
      s8b b = ((const s8b*)&stage[kc][(ntp*2+i2)*512])[l];
      acc[i2] = MFMA16(af[kc], b, acc[i2]);
    }
  }
  asm volatile("s_waitcnt vmcnt(0)" ::: "memory");
  __syncthreads();
  #pragma unroll
  for (int kc=8;kc<16;++kc){
    #pragma unroll
    for (int i2=0;i2<2;++i2){
      s8b b = ((const s8b*)&stage[kc][(ntp*2+i2)*512])[l];
      acc[i2] = MFMA16(af[kc], b, acc[i2]);
    }
  }
  if (mode==0){
    #pragma unroll
    for (int i2=0;i2<2;++i2){
      const int col = cg*128 + (ntp*2+i2)*16 + lm;
      #pragma unroll
      for (int q=0;q<4;++q){
        const int r = mt*16 + g*4 + q;
        zF_out[(size_t)(row0+r)*HD + col] = sigf(acc[i2][q] + bias_tab[codes_s[r]*HD + col]);
      }
    }
  } else if (mode==1){
    #pragma unroll
    for (int i2=0;i2<2;++i2){
      const int col = cg*128 + (ntp*2+i2)*16 + lm;
      #pragma unroll
      for (int q=0;q<4;++q){
        const int r = mt*16 + g*4 + q;
        const size_t idx = (size_t)(row0+r)*HD + col;
        float pre = tanhf_fast(acc[i2][q] + bias_tab[codes_s[r]*HD + col]);
        float zv = zF_in[idx];
        float m = (1.f - zv)*sumhF[idx] + zv*pre;
        hF[idx] = m;
        hB[idx] = (short)f2bf(m);
      }
    }
  } else {
    float p[4];
    #pragma unroll
    for (int q=0;q<4;++q) p[q]=0.f;
    #pragma unroll
    for (int i2=0;i2<2;++i2){
      const int col = cg*128 + (ntp*2+i2)*16 + lm;
      float wv = w_topo[col];
      float bnl = bias_tab[col];
      #pragma unroll
      for (int q=0;q<4;++q){
        float hid = fmaxf(acc[i2][q] + bnl, 0.f);
        p[q] = fmaf(hid, wv, p[q]);
      }
    }
    #pragma unroll
    for (int s=1;s<16;s<<=1)
      #pragma unroll
      for (int q=0;q<4;++q) p[q] += __shfl_xor(p[q], s);
    if (lm==0){
      #pragma unroll
      for (int q=0;q<4;++q)
        topo_p[(size_t)(cg*4+ntp)*NROWS + row0 + mt*16 + g*4 + q] = p[q];
    }
  }
}

// r gate over all (n,k) rows + in-block k-reduction -> sum_gated bf16.
// grid (512 row-tiles x 4 cg), block owns 32 h_nei rows = 4 complete nodes.
__global__ __launch_bounds__(512) void ggru_r_k(
    const short* __restrict__ fUr,
    const float* __restrict__ h_nei,
    const int* __restrict__ hpn_idx,
    const float* __restrict__ wxbr_mp,
    short* __restrict__ sgB)
{
  __shared__ __align__(16) short stage[16][4096];
  __shared__ float gat[32][128];
  __shared__ int codes_s[32];
  const int tt = threadIdx.x, l = tt&63, w = tt>>6, lm = l&15, g = l>>4;
  const int rt = blockIdx.x, row0 = rt*32, cg = blockIdx.y;
  if (tt<32) codes_s[tt] = hpn_idx[(row0+tt)>>3];
  const int mt = w>>2, ntp = w&3;
  const short* gsrc = fUr + ((size_t)(cg*8 + w)*16)*512 + (size_t)l*8;
  #pragma unroll
  for (int kc=0;kc<8;++kc) dma16(gsrc + (size_t)kc*512, &stage[kc][w*512 + l*8]);
  s8b af[16];
  {
    const float* hrow = h_nei + (size_t)(row0 + mt*16 + lm)*HD;
    #pragma unroll
    for (int kc=0;kc<16;++kc){
      float4 v0 = *(const float4*)&hrow[kc*32 + g*8];
      float4 v1 = *(const float4*)&hrow[kc*32 + g*8 + 4];
      s8b a;
      a[0]=(short)f2bf(v0.x); a[1]=(short)f2bf(v0.y); a[2]=(short)f2bf(v0.z); a[3]=(short)f2bf(v0.w);
      a[4]=(short)f2bf(v1.x); a[5]=(short)f2bf(v1.y); a[6]=(short)f2bf(v1.z); a[7]=(short)f2bf(v1.w);
      af[kc] = a;
    }
  }
  asm volatile("s_waitcnt vmcnt(0)" ::: "memory");
  __syncthreads();
  #pragma unroll
  for (int kc=8;kc<16;++kc) dma16(gsrc + (size_t)kc*512, &stage[kc][w*512 + l*8]);
  f4 acc[2]; acc[0]=f4zero(); acc[1]=f4zero();
  #pragma unroll
  for (int kc=0;kc<8;++kc){
    #pragma unroll
    for (int i2=0;i2<2;++i2){
      s8b b = ((const s8b*)&stage[kc][(ntp*2+i2)*512])[l];
      acc[i2] = MFMA16(af[kc], b, acc[i2]);
    }
  }
  asm volatile("s_waitcnt vmcnt(0)" ::: "memory");
  __syncthreads();
  #pragma unroll
  for (int kc=8;kc<16;++kc){
    #pragma unroll
    for (int i2=0;i2<2;++i2){
      s8b b = ((const s8b*)&stage[kc][(ntp*2+i2)*512])[l];
      acc[i2] = MFMA16(af[kc], b, acc[i2]);
    }
  }
  #pragma unroll
  for (int i2=0;i2<2;++i2){
    const int lc = (ntp*2+i2)*16 + lm;
    const int col = cg*128 + lc;
    #pragma unroll
    for (int q=0;q<4;++q){
      const int r = mt*16 + g*4 + q;
      float rv = sigf(acc[i2][q] + wxbr_mp[codes_s[r]*HD + col]);
      gat[r][lc] = rv * h_nei[(size_t)(row0+r)*HD + col];
    }
  }
  __syncthreads();
  {
    int j = tt >> 7, c = tt & 127;   // 4 nodes x 128 cols
    float s = 0.f;
    #pragma unroll
    for (int k=0;k<8;++k) s += gat[j*8+k][c];
    sgB[(size_t)(rt*4 + j)*HD + cg*128 + c] = (short)f2bf(s);
  }
}

// ---------------- scan step kernel A: z, r, nuc GEMMs on h(t) ----------------
__global__ __launch_bounds__(512) void zrnuc_k(
    int t, const int* __restrict__ nuc_idx,
    const short* __restrict__ fz, const short* __restrict__ fr, const short* __restrict__ fnuc,
    const short* __restrict__ hB, const float* __restrict__ hF,
    const float* __restrict__ wxbz, const float* __restrict__ wxbr,
    const float* __restrict__ latp, const float* __restrict__ w_nuc,
    float* __restrict__ zF, short* __restrict__ ghB, float* __restrict__ nucp)
{
  const int cg = blockIdx.y;
  const int mat = cg>>2;
  if (t==0 && mat==2) return;
  __shared__ __align__(16) short stage[16][4096];
  __shared__ int codes_s[64];
  const int tt = threadIdx.x, l = tt&63, w = tt>>6, lm = l&15, g = l>>4;
  const int rt = blockIdx.x, row0 = rt*64;
  const short* frag = (mat==0)?fz:((mat==1)?fr:fnuc);
  const int otb = (cg&3)*8;
  if (tt<64) codes_s[tt] = nuc_idx[(size_t)(row0+tt)*LSEQ + t];
  const int mt = w>>1, nh2 = w&1;
  const short* gsrc = frag + ((size_t)(otb + w)*16)*512 + (size_t)l*8;
  #pragma unroll
  for (int kc=0;kc<8;++kc) dma16(gsrc + (size_t)kc*512, &stage[kc][w*512 + l*8]);
  s8b af[16];
  {
    const s8b* hrow = (const s8b*)(hB + (size_t)(row0 + mt*16 + lm)*HD);
    #pragma unroll
    for (int kc=0;kc<16;++kc) af[kc] = hrow[kc*4 + g];
  }
  asm volatile("s_waitcnt vmcnt(0)" ::: "memory");
  __syncthreads();
  #pragma unroll
  for (int kc=8;kc<16;++kc) dma16(gsrc + (size_t)kc*512, &stage[kc][w*512 + l*8]);
  f4 acc[4];
  #pragma unroll
  for (int i=0;i<4;++i) acc[i]=f4zero();
  #pragma unroll
  for (int kc=0;kc<8;++kc){
    #pragma unroll
    for (int i=0;i<4;++i){
      s8b b = ((const s8b*)&stage[kc][(nh2*4+i)*512])[l];
      acc[i] = MFMA16(af[kc], b, acc[i]);
    }
  }
  asm volatile("s_waitcnt vmcnt(0)" ::: "memory");
  __syncthreads();
  #pragma unroll
  for (int kc=8;kc<16;++kc){
    #pragma unroll
    for (int i=0;i<4;++i){
      s8b b = ((const s8b*)&stage[kc][(nh2*4+i)*512])[l];
      acc[i] = MFMA16(af[kc], b, acc[i]);
    }
  }
  const int colb = (cg&3)*128;
  if (mat==0){
    #pragma unroll
    for (int i=0;i<4;++i){
      const int col = colb + (nh2*4+i)*16 + lm;
      #pragma unroll
      for (int q=0;q<4;++q){
        const int r = mt*16 + g*4 + q;
        float zv = sigf(acc[i][q] + wxbz[codes_s[r]*HD + col]);
        zF[(size_t)(row0+r)*HD + col] = zv;
      }
    }
  } else if (mat==1){
    #pragma unroll
    for (int i=0;i<4;++i){
      const int col = colb + (nh2*4+i)*16 + lm;
      #pragma unroll
      for (int q=0;q<4;++q){
        const int r = mt*16 + g*4 + q;
        float rv = sigf(acc[i][q] + wxbr[codes_s[r]*HD + col]);
        ghB[(size_t)(row0+r)*HD + col] = (short)f2bf(rv * hF[(size_t)(row0+r)*HD + col]);
      }
    }
  } else {
    float p[4][NNUC];
    #pragma unroll
    for (int q=0;q<4;++q)
      #pragma unroll
      for (int j=0;j<NNUC;++j) p[q][j]=0.f;
    #pragma unroll
    for (int i=0;i<4;++i){
      const int col = colb + (nh2*4+i)*16 + lm;
      #pragma unroll
      for (int q=0;q<4;++q){
        const int r = mt*16 + g*4 + q;
        float hid = fmaxf(acc[i][q] + latp[(size_t)(row0+r)*HD + col], 0.f);
        #pragma unroll
        for (int j=0;j<NNUC;++j) p[q][j] = fmaf(hid, w_nuc[(size_t)j*HD + col], p[q][j]);
      }
    }
    #pragma unroll
    for (int s=1;s<16;s<<=1)
      #pragma unroll
      for (int q=0;q<4;++q)
        #pragma unroll
        for (int j=0;j<NNUC;++j) p[q][j] += __shfl_xor(p[q][j], s);
    if (lm==0){
      const int slab = (cg&3)*2 + nh2;
      #pragma unroll
      for (int q=0;q<4;++q){
        const int row = row0 + mt*16 + g*4 + q;
        #pragma unroll
        for (int j=0;j<NNUC;++j)
          nucp[((size_t)slab*NROWS + row)*NNUC + j] = p[q][j];
      }
    }
  }
}

// ---------------- scan step kernel B: candidate GEMM + h update ----------------
__global__ __launch_bounds__(512) void cand_k(
    int t, const int* __restrict__ nuc_idx,
    const short* __restrict__ fh,
    const short* __restrict__ ghB,
    const float* __restrict__ wxbh,
    const float* __restrict__ zF, float* __restrict__ hF, short* __restrict__ hB,
    const float* __restrict__ nucp, const float* __restrict__ b_nuc,
    float* __restrict__ out_nuc)
{
  __shared__ __align__(16) short stage[16][4096];
  __shared__ int codes_s[32];
  const int tt = threadIdx.x, l = tt&63, w = tt>>6, lm = l&15, g = l>>4;
  const int rt = blockIdx.x, row0 = rt*32, cg = blockIdx.y;
  if (tt<32) codes_s[tt] = nuc_idx[(size_t)(row0+tt)*LSEQ + t];
  const int mt = w>>2, ntp = w&3;
  const short* gsrc = fh + ((size_t)(cg*8 + w)*16)*512 + (size_t)l*8;
  #pragma unroll
  for (int kc=0;kc<8;++kc) dma16(gsrc + (size_t)kc*512, &stage[kc][w*512 + l*8]);
  s8b af[16];
  {
    const s8b* grow = (const s8b*)(ghB + (size_t)(row0 + mt*16 + lm)*HD);
    #pragma unroll
    for (int kc=0;kc<16;++kc) af[kc] = grow[kc*4 + g];
  }
  asm volatile("s_waitcnt vmcnt(0)" ::: "memory");
  __syncthreads();
  #pragma unroll
  for (int kc=8;kc<16;++kc) dma16(gsrc + (size_t)kc*512, &stage[kc][w*512 + l*8]);
  f4 acc[2]; acc[0]=f4zero(); acc[1]=f4zero();
  #pragma unroll
  for (int kc=0;kc<8;++kc){
    #pragma unroll
    for (int i2=0;i2<2;++i2){
      s8b b = ((const s8b*)&stage[kc][(ntp*2+i2)*512])[l];
      acc[i2] = MFMA16(af[kc], b, acc[i2]);
    }
  }
  asm volatile("s_waitcnt vmcnt(0)" ::: "memory");
  __syncthreads();
  #pragma unroll
  for (int kc=8;kc<16;++kc){
    #pragma unroll
    for (int i2=0;i2<2;++i2){
      s8b b = ((const s8b*)&stage[kc][(ntp*2+i2)*512])[l];
      acc[i2] = MFMA16(af[kc], b, acc[i2]);
    }
  }
  #pragma unroll
  for (int i2=0;i2<2;++i2){
    const int col = cg*128 + (ntp*2+i2)*16 + lm;
    #pragma unroll
    for (int q=0;q<4;++q){
      const int r = mt*16 + g*4 + q;
      const size_t idx = (size_t)(row0+r)*HD + col;
      float pre = tanhf_fast(acc[i2][q] + wxbh[codes_s[r]*HD + col]);
      float zv = zF[idx];
      float hn = (1.f - zv)*hF[idx] + zv*pre;
      hF[idx] = hn;
      hB[idx] = (short)f2bf(hn);
    }
  }
  if (t > 0 && cg == 0 && tt < 32*NNUC){
    int rr = tt/NNUC, j = tt - rr*NNUC;
    int row = row0 + rr;
    float s2 = b_nuc[j];
    #pragma unroll
    for (int s8=0;s8<8;++s8) s2 += nucp[((size_t)s8*NROWS + row)*NNUC + j];
    out_nuc[((size_t)row*LSEQ + (t-1))*NNUC + j] = s2;
  }
}

// ---------------- tail heads: nuc(l=63) + hpn on h(64) ----------------
__global__ __launch_bounds__(512) void heads_k(
    const short* __restrict__ fnuc, const short* __restrict__ fhpn,
    const short* __restrict__ hB,
    const float* __restrict__ latp, const float* __restrict__ w_nuc,
    const float* __restrict__ b_hpn_nl, const float* __restrict__ w_hpn,
    float* __restrict__ nucpH, float* __restrict__ hpnp)
{
  __shared__ __align__(16) short stage[16][4096];
  const int tt = threadIdx.x, l = tt&63, w = tt>>6, lm = l&15, g = l>>4;
  const int rt = blockIdx.x, row0 = rt*32, cg = blockIdx.y;
  const int mat = cg>>2;
  const short* frag = mat ? fhpn : fnuc;
  const int mt = w>>2, ntp = w&3;
  const short* gsrc = frag + ((size_t)((cg&3)*8 + w)*16)*512 + (size_t)l*8;
  #pragma unroll
  for (int kc=0;kc<8;++kc) dma16(gsrc + (size_t)kc*512, &stage[kc][w*512 + l*8]);
  s8b af[16];
  {
    const s8b* hrow = (const s8b*)(hB + (size_t)(row0 + mt*16 + lm)*HD);
    #pragma unroll
    for (int kc=0;kc<16;++kc) af[kc] = hrow[kc*4 + g];
  }
  asm volatile("s_waitcnt vmcnt(0)" ::: "memory");
  __syncthreads();
  #pragma unroll
  for (int kc=8;kc<16;++kc) dma16(gsrc + (size_t)kc*512, &stage[kc][w*512 + l*8]);
  f4 acc[2]; acc[0]=f4zero(); acc[1]=f4zero();
  #pragma unroll
  for (int kc=0;kc<8;++kc){
    #pragma unroll
    for (int i2=0;i2<2;++i2){
      s8b b = ((const s8b*)&stage[kc][(ntp*2+i2)*512])[l];
      acc[i2] = MFMA16(af[kc], b, acc[i2]);
    }
  }
  asm volatile("s_waitcnt vmcnt(0)" ::: "memory");
  __syncthreads();
  #pragma unroll
  for (int kc=8;kc<16;++kc){
    #pragma unroll
    for (int i2=0;i2<2;++i2){
      s8b b = ((const s8b*)&stage[kc][(ntp*2+i2)*512])[l];
      acc[i2] = MFMA16(af[kc], b, acc[i2]);
    }
  }
  const int slab = (cg&3)*4 + ntp;
  if (mat==0){
    float p[4][NNUC];
    #pragma unroll
    for (int q=0;q<4;++q)
      #pragma unroll
      for (int j=0;j<NNUC;++j) p[q][j]=0.f;
    #pragma unroll
    for (int i2=0;i2<2;++i2){
      const int col = (cg&3)*128 + (ntp*2+i2)*16 + lm;
      #pragma unroll
      for (int q=0;q<4;++q){
        const int r = mt*16 + g*4 + q;
        float hid = fmaxf(acc[i2][q] + latp[(size_t)(row0+r)*HD + col], 0.f);
        #pragma unroll
        for (int j=0;j<NNUC;++j) p[q][j] = fmaf(hid, w_nuc[(size_t)j*HD + col], p[q][j]);
      }
    }
    #pragma unroll
    for (int s=1;s<16;s<<=1)
      #pragma unroll
      for (int q=0;q<4;++q)
        #pragma unroll
        for (int j=0;j<NNUC;++j) p[q][j] += __shfl_xor(p[q][j], s);
    if (lm==0){
      #pragma unroll
      for (int q=0;q<4;++q){
        const int row = row0 + mt*16 + g*4 + q;
        #pragma unroll
        for (int j=0;j<NNUC;++j)
          nucpH[((size_t)slab*NROWS + row)*NNUC + j] = p[q][j];
      }
    }
  } else {
    float p[4][NHPN];
    #pragma unroll
    for (int q=0;q<4;++q)
      #pragma unroll
      for (int j=0;j<NHPN;++j) p[q][j]=0.f;
    #pragma unroll
    for (int i2=0;i2<2;++i2){
      const int col = (cg&3)*128 + (ntp*2+i2)*16 + lm;
      float bnl = b_hpn_nl[col];
      #pragma unroll
      for (int q=0;q<4;++q){
        float hid = fmaxf(acc[i2][q] + bnl, 0.f);
        #pragma unroll
        for (int j=0;j<NHPN;++j) p[q][j] = fmaf(hid, w_hpn[(size_t)j*HD + col], p[q][j]);
      }
    }
    #pragma unroll
    for (int s=1;s<16;s<<=1)
      #pragma unroll
      for (int q=0;q<4;++q)
        #pragma unroll
        for (int j=0;j<NHPN;++j) p[q][j] += __shfl_xor(p[q][j], s);
    if (lm==0){
      #pragma unroll
      for (int q=0;q<4;++q){
        const int row = row0 + mt*16 + g*4 + q;
        #pragma unroll
        for (int j=0;j<NHPN;++j)
          hpnp[((size_t)slab*NROWS + row)*NHPN + j] = p[q][j];
      }
    }
  }
}

__global__ void final_red_k(const float* __restrict__ nucpH, const float* __restrict__ hpnp,
    const float* __restrict__ topo_p,
    const float* __restrict__ b_nuc, const float* __restrict__ b_hpn, const float* __restrict__ b_topo,
    const float* __restrict__ hF,
    float* __restrict__ out_newh, float* __restrict__ out_hpn, float* __restrict__ out_nuc,
    float* __restrict__ out_stop)
{
  int gid = blockIdx.x*256 + threadIdx.x;   // grid 128x256 = 32768
  if (gid < NROWS*NNUC){
    int n = gid/NNUC, j = gid - n*NNUC;
    float s = b_nuc[j];
    #pragma unroll
    for (int s8=0;s8<16;++s8) s += nucpH[((size_t)s8*NROWS + n)*NNUC + j];
    out_nuc[((size_t)n*LSEQ + 63)*NNUC + j] = s;
  } else if (gid < NROWS*NNUC + NROWS*NHPN){
    int g2 = gid - NROWS*NNUC;
    int n = g2/NHPN, j = g2 - n*NHPN;
    float s = b_hpn[j];
    #pragma unroll
    for (int s8=0;s8<16;++s8) s += hpnp[((size_t)s8*NROWS + n)*NHPN + j];
    out_hpn[(size_t)n*NHPN + j] = s;
  } else if (gid < NROWS*NNUC + NROWS*NHPN + NROWS){
    int n = gid - (NROWS*NNUC + NROWS*NHPN);
    float s = b_topo[0];
    #pragma unroll
    for (int s16=0;s16<16;++s16) s += topo_p[(size_t)s16*NROWS + n];
    out_stop[n] = s;
  }
  const float4* src = (const float4*)hF;
  float4* dst = (float4*)out_newh;
  for (int i = gid; i < NROWS*HD/4; i += 32768) dst[i] = src[i];
}

// ---------------- host ----------------
extern "C" void kernel_launch(void* const* d_in, const int* in_sizes, int n_in,
                              void* d_out, int out_size, void* d_ws, size_t ws_size,
                              hipStream_t stream_){
  (void)in_sizes; (void)n_in; (void)out_size; (void)ws_size;
  const int*   hpn_idx      = (const int*)d_in[0];
  const int*   nuc_idx      = (const int*)d_in[1];
  const float* h_nei        = (const float*)d_in[2];
  const float* graph_latent = (const float*)d_in[3];
  const float* Wz_mp=(const float*)d_in[4];  const float* bz_mp=(const float*)d_in[5];
  const float* Wr_mp=(const float*)d_in[6];  const float* br_mp=(const float*)d_in[7];
  const float* Ur_mp=(const float*)d_in[8];
  const float* Wh_mp=(const float*)d_in[9];  const float* bh_mp=(const float*)d_in[10];
  const float* Wz_nuc=(const float*)d_in[11]; const float* bz_nuc=(const float*)d_in[12];
  const float* Wr_nuc=(const float*)d_in[13]; const float* br_nuc=(const float*)d_in[14];
  const float* Wh_nuc=(const float*)d_in[15]; const float* bh_nuc=(const float*)d_in[16];
  const float* W_hpn_nl=(const float*)d_in[17]; const float* b_hpn_nl=(const float*)d_in[18];
  const float* W_hpn=(const float*)d_in[19];  const float* b_hpn=(const float*)d_in[20];
  const float* W_nuc_nl=(const float*)d_in[21]; const float* b_nuc_nl=(const float*)d_in[22];
  const float* W_nuc=(const float*)d_in[23];  const float* b_nuc=(const float*)d_in[24];
  const float* W_topo_nl=(const float*)d_in[25]; const float* b_topo_nl=(const float*)d_in[26];
  const float* W_topo=(const float*)d_in[27]; const float* b_topo=(const float*)d_in[28];

  float* ws = (float*)d_ws;
  size_t off = 0;
  auto take = [&](size_t nfl){ float* p = ws + off; off += nfl; return p; };
  float* wt_nl_lat = take((size_t)LATD*HD);
  // scan bf16 fragment weights
  short* fz    = (short*)take((size_t)HD*HD/2);
  short* fr    = (short*)take((size_t)HD*HD/2);
  short* fh    = (short*)take((size_t)HD*HD/2);
  short* fnuc  = (short*)take((size_t)HD*HD/2);
  short* fhpn  = (short*)take((size_t)HD*HD/2);
  // graphgru bf16 fragment weights
  short* fWzh  = (short*)take((size_t)HD*HD/2);
  short* fUr   = (short*)take((size_t)HD*HD/2);
  short* fWhh  = (short*)take((size_t)HD*HD/2);
  short* fWtopo= (short*)take((size_t)HD*HD/2);
  float* wxbz = take((size_t)NNUC*HD);
  float* wxbr = take((size_t)NNUC*HD);
  float* wxbh = take((size_t)NNUC*HD);
  float* wxbz_mp = take((size_t)NHPN*HD);
  float* wxbr_mp = take((size_t)NHPN*HD);
  float* wxbh_mp = take((size_t)NHPN*HD);
  float* latp = take((size_t)NROWS*HD);
  float* hF   = take((size_t)NROWS*HD);
  short* hB   = (short*)take((size_t)NROWS*HD/2);
  short* ghB  = (short*)take((size_t)NROWS*HD/2);
  float* zF   = take((size_t)NROWS*HD);
  float* sumhF = take((size_t)NROWS*HD);
  short* sumhB = (short*)take((size_t)NROWS*HD/2);
  short* sgB   = (short*)take((size_t)NROWS*HD/2);
  float* nucp = take((size_t)8*NROWS*NNUC);
  float* nucpH= take((size_t)16*NROWS*NNUC);
  float* hpnp = take((size_t)16*NROWS*NHPN);
  float* topo_p = take((size_t)16*NROWS);

  float* out       = (float*)d_out;
  float* out_newh  = out;
  float* out_hpn   = out + (size_t)NROWS*HD;
  float* out_nuc   = out_hpn + (size_t)NROWS*NHPN;
  float* out_stop  = out_nuc + (size_t)NROWS*LSEQ*NNUC;

  transpose_w<<<(LATD*HD+255)/256, 256, 0, stream_>>>(W_nuc_nl, wt_nl_lat, HD+LATD, HD, LATD);

  const int FB = (HD*HD+255)/256;
  fragprep_k<<<FB,256,0,stream_>>>(Wz_nuc,   fz,    HD+NNUC, NNUC);
  fragprep_k<<<FB,256,0,stream_>>>(Wr_nuc,   fr,    HD+NNUC, NNUC);
  fragprep_k<<<FB,256,0,stream_>>>(Wh_nuc,   fh,    HD+NNUC, NNUC);
  fragprep_k<<<FB,256,0,stream_>>>(W_nuc_nl, fnuc,  HD+LATD, 0);
  fragprep_k<<<FB,256,0,stream_>>>(W_hpn_nl, fhpn,  HD,      0);
  fragprep_k<<<FB,256,0,stream_>>>(Wz_mp,    fWzh,  HD+NHPN, NHPN);
  fragprep_k<<<FB,256,0,stream_>>>(Ur_mp,    fUr,   HD,      0);
  fragprep_k<<<FB,256,0,stream_>>>(Wh_mp,    fWhh,  HD+NHPN, NHPN);
  fragprep_k<<<FB,256,0,stream_>>>(W_topo_nl,fWtopo,HD,      0);

  const int WB = (NNUC*HD+255)/256;
  wxbprep2_k<<<WB,256,0,stream_>>>(Wz_nuc, bz_nuc, wxbz, HD+NNUC, NNUC);
  wxbprep2_k<<<WB,256,0,stream_>>>(Wr_nuc, br_nuc, wxbr, HD+NNUC, NNUC);
  wxbprep2_k<<<WB,256,0,stream_>>>(Wh_nuc, bh_nuc, wxbh, HD+NNUC, NNUC);
  const int WB2 = (NHPN*HD+255)/256;
  wxbprep2_k<<<WB2,256,0,stream_>>>(Wz_mp, bz_mp, wxbz_mp, HD+NHPN, NHPN);
  wxbprep2_k<<<WB2,256,0,stream_>>>(Wr_mp, br_mp, wxbr_mp, NHPN,    NHPN);
  wxbprep2_k<<<WB2,256,0,stream_>>>(Wh_mp, bh_mp, wxbh_mp, HD+NHPN, NHPN);

  latp_k<<<NROWS/16, 512, 0, stream_>>>(graph_latent, wt_nl_lat, b_nuc_nl, latp);

  // ---- GraphGRU via MFMA ----
  sumcast_k<<<512, 512, 0, stream_>>>(h_nei, sumhF, sumhB);
  ggru_gemm_k<<<dim3(64,4), 512, 0, stream_>>>(
      0, fWzh, sumhB, hpn_idx, wxbz_mp, nullptr, nullptr, nullptr,
      zF, nullptr, nullptr, nullptr);
  ggru_r_k<<<dim3(512,4), 512, 0, stream_>>>(fUr, h_nei, hpn_idx, wxbr_mp, sgB);
  ggru_gemm_k<<<dim3(64,4), 512, 0, stream_>>>(
      1, fWhh, sgB, hpn_idx, wxbh_mp, sumhF, zF, nullptr,
      nullptr, hF, hB, nullptr);
  ggru_gemm_k<<<dim3(64,4), 512, 0, stream_>>>(
      2, fWtopo, hB, hpn_idx, b_topo_nl, nullptr, nullptr, W_topo,
      nullptr, nullptr, nullptr, topo_p);

  // ---- scan ----
  for (int t = 0; t < LSEQ; ++t){
    zrnuc_k<<<dim3(32,12), 512, 0, stream_>>>(
        t, nuc_idx, fz, fr, fnuc, hB, hF,
        wxbz, wxbr, latp, W_nuc, zF, ghB, nucp);
    cand_k<<<dim3(64,4), 512, 0, stream_>>>(
        t, nuc_idx, fh, ghB, wxbh, zF, hF, hB,
        nucp, b_nuc, out_nuc);
  }

  heads_k<<<dim3(64,8), 512, 0, stream_>>>(
      fnuc, fhpn, hB, latp, W_nuc, b_hpn_nl, W_hpn, nucpH, hpnp);
  final_red_k<<<128, 256, 0, stream_>>>(
      nucpH, hpnp, topo_p, b_nuc, b_hpn, b_topo, hF,
      out_newh, out_hpn, out_nuc, out_stop);
}

// Round 11
// 1850.596 us; speedup vs baseline: 3.4852x; 1.1522x over previous
//
#include <hip/hip_runtime.h>
#include <math.h>

#define NROWS 2048
#define KNEI  8
#define LSEQ  64
#define HD    512
#define HD4   128
#define LATD  128
#define NHPN  4
#define NNUC  5

typedef __attribute__((ext_vector_type(8))) short s8b;   // 8 bf16 (16B)
typedef __attribute__((ext_vector_type(4))) short s4b;   // 4 bf16 (8B)
typedef __attribute__((ext_vector_type(4))) float f4;    // MFMA acc

#define MFMA16(a,b,c) __builtin_amdgcn_mfma_f32_16x16x32_bf16(a,b,c,0,0,0)

__device__ __forceinline__ f4 f4zero(){ f4 z; z[0]=0.f; z[1]=0.f; z[2]=0.f; z[3]=0.f; return z; }
__device__ __forceinline__ float sigf(float x){ return __fdividef(1.0f, 1.0f + __expf(-x)); }
__device__ __forceinline__ float tanhf_fast(float x){
  float e = __expf(-2.0f*fabsf(x));
  float t = __fdividef(1.0f - e, 1.0f + e);
  return x >= 0.f ? t : -t;
}
__device__ __forceinline__ unsigned short f2bf(float x){
  union{float f; unsigned u;} v; v.f = x;
  unsigned r = (v.u + 0x7FFFu + ((v.u>>16)&1u)) >> 16;
  return (unsigned short)r;
}
__device__ __forceinline__ float bf2f(unsigned short u){
  union{unsigned x; float f;} v; v.x = ((unsigned)u)<<16; return v.f;
}
__device__ __forceinline__ void add4(float4& a, float4 b){ a.x+=b.x; a.y+=b.y; a.z+=b.z; a.w+=b.w; }

__device__ __forceinline__ void dma16(const short* g, const short* l){
  __builtin_amdgcn_global_load_lds(
      (const __attribute__((address_space(1))) void*)(unsigned long long)g,
      (__attribute__((address_space(3))) void*)(unsigned long long)l,
      16, 0, 0);
}

// ---------------- prep kernels ----------------

__global__ void transpose_w(const float* __restrict__ src, float* __restrict__ dst,
                            int src_cols, int col_off, int nh){
  int idx = blockIdx.x*256 + threadIdx.x;
  if (idx >= nh*HD) return;
  int h = idx / HD, o = idx - h*HD;
  dst[idx] = src[o*src_cols + col_off + h];
}

// B-frag layout (per 16x16x32 tile, 1KB): dst[tile*512 + l*8 + j] = W[n][k]
__global__ void fragprep_k(const float* __restrict__ W, short* __restrict__ dst,
                           int src_cols, int col_off){
  int idx = blockIdx.x*256 + threadIdx.x;
  if (idx >= HD*HD) return;
  int j = idx&7, l = (idx>>3)&63, tile = idx>>9;
  int kc = tile&15, ot = tile>>4;
  int row = ot*16 + (l&15), k = kc*32 + (l>>4)*8 + j;
  dst[idx] = (short)f2bf(W[(size_t)row*src_cols + col_off + k]);
}

// wxb[c*HD + n] = W[n][c] + b[n]   (nc codes)
__global__ void wxbprep2_k(const float* __restrict__ W, const float* __restrict__ b,
                           float* __restrict__ dst, int src_cols, int nc){
  int idx = blockIdx.x*256 + threadIdx.x;
  if (idx >= nc*HD) return;
  int c = idx/HD, n = idx - c*HD;
  dst[idx] = W[(size_t)n*src_cols + c] + b[n];
}

// latp[n][o] = b_nl[o] + sum_q gl[n][q]*wtlat[q*HD+o]
__global__ __launch_bounds__(512) void latp_k(const float* __restrict__ gl, const float* __restrict__ wtlat,
                     const float* __restrict__ bnl, float* __restrict__ latp){
  __shared__ float gls[16][LATD];
  int b = blockIdx.x, t = threadIdx.x;
  for (int i=t;i<16*LATD;i+=512) gls[i/LATD][i%LATD] = gl[(size_t)(b*16)*LATD + i];
  __syncthreads();
  float acc[16];
  float bv = bnl[t];
  #pragma unroll
  for (int r=0;r<16;++r) acc[r]=bv;
  for (int q=0;q<LATD;++q){
    float wv = wtlat[(size_t)q*HD + t];
    #pragma unroll
    for (int r=0;r<16;++r) acc[r] = fmaf(gls[r][q], wv, acc[r]);
  }
  #pragma unroll
  for (int r=0;r<16;++r) latp[(size_t)(b*16+r)*HD + t] = acc[r];
}

// sumh = h_nei.sum(k): fp32 + bf16 copies; also bf16 copy of full h_nei (hnB).
__global__ void sumcast_k(const float* __restrict__ h_nei,
                          float* __restrict__ sumhF, short* __restrict__ sumhB,
                          short* __restrict__ hnB){
  int idx = blockIdx.x*512 + threadIdx.x;
  int n = idx >> 7, c4 = idx & 127;
  const float4* hn4 = (const float4*)h_nei;
  size_t base = (size_t)n*KNEI*HD4 + c4;
  float4 s = make_float4(0.f,0.f,0.f,0.f);
  #pragma unroll
  for (int k=0;k<KNEI;++k){
    float4 v = hn4[base + (size_t)k*HD4];
    add4(s, v);
    s4b pb;
    pb[0]=(short)f2bf(v.x); pb[1]=(short)f2bf(v.y); pb[2]=(short)f2bf(v.z); pb[3]=(short)f2bf(v.w);
    ((s4b*)hnB)[(size_t)(n*KNEI + k)*HD4 + c4] = pb;
  }
  ((float4*)sumhF)[(size_t)n*HD4 + c4] = s;
  s4b p;
  p[0]=(short)f2bf(s.x); p[1]=(short)f2bf(s.y); p[2]=(short)f2bf(s.z); p[3]=(short)f2bf(s.w);
  ((s4b*)sumhB)[(size_t)n*HD4 + c4] = p;
}

// ---------------- GraphGRU MFMA GEMMs ----------------
// Shared core: grid (64 row-tiles x 4 cg), 512 thr, 32 rows x 128 cols.
// mode: 0 = z gate, 1 = candidate+msg, 2 = topo head.
__global__ __launch_bounds__(512) void ggru_gemm_k(
    int mode,
    const short* __restrict__ frag,
    const short* __restrict__ A,
    const int* __restrict__ hpn_idx,
    const float* __restrict__ bias_tab,
    const float* __restrict__ sumhF, const float* __restrict__ zF_in,
    const float* __restrict__ w_topo,
    float* __restrict__ zF_out,
    float* __restrict__ hF, short* __restrict__ hB,
    float* __restrict__ topo_p)
{
  __shared__ __align__(16) short stage[16][4096];
  __shared__ int codes_s[32];
  const int tt = threadIdx.x, l = tt&63, w = tt>>6, lm = l&15, g = l>>4;
  const int rt = blockIdx.x, row0 = rt*32, cg = blockIdx.y;
  if (tt<32) codes_s[tt] = hpn_idx[row0+tt];
  const int mt = w>>2, ntp = w&3;
  const short* gsrc = frag + ((size_t)(cg*8 + w)*16)*512 + (size_t)l*8;
  #pragma unroll
  for (int kc=0;kc<8;++kc) dma16(gsrc + (size_t)kc*512, &stage[kc][w*512 + l*8]);
  s8b af[16];
  {
    const s8b* arow = (const s8b*)(A + (size_t)(row0 + mt*16 + lm)*HD);
    #pragma unroll
    for (int kc=0;kc<16;++kc) af[kc] = arow[kc*4 + g];
  }
  asm volatile("s_waitcnt vmcnt(0)" ::: "memory");
  __syncthreads();
  #pragma unroll
  for (int kc=8;kc<16;++kc) dma16(gsrc + (size_t)kc*512, &stage[kc][w*512 + l*8]);
  f4 acc[2]; acc[0]=f4zero(); acc[1]=f4zero();
  #pragma unroll
  for (int kc=0;kc<8;++kc){
    #pragma unroll
    for (int i2=0;i2<2;++i2){
      s8b b = ((const s8b*)&stage[kc][(ntp*2+i2)*512])[l];
      acc[i2] = MFMA16(af[kc], b, acc[i2]);
    }
  }
  asm volatile("s_waitcnt vmcnt(0)" ::: "memory");
  __syncthreads();
  #pragma unroll
  for (int kc=8;kc<16;++kc){
    #pragma unroll
    for (int i2=0;i2<2;++i2){
      s8b b = ((const s8b*)&stage[kc][(ntp*2+i2)*512])[l];
      acc[i2] = MFMA16(af[kc], b, acc[i2]);
    }
  }
  if (mode==0){
    #pragma unroll
    for (int i2=0;i2<2;++i2){
      const int col = cg*128 + (ntp*2+i2)*16 + lm;
      #pragma unroll
      for (int q=0;q<4;++q){
        const int r = mt*16 + g*4 + q;
        zF_out[(size_t)(row0+r)*HD + col] = sigf(acc[i2][q] + bias_tab[codes_s[r]*HD + col]);
      }
    }
  } else if (mode==1){
    #pragma unroll
    for (int i2=0;i2<2;++i2){
      const int col = cg*128 + (ntp*2+i2)*16 + lm;
      #pragma unroll
      for (int q=0;q<4;++q){
        const int r = mt*16 + g*4 + q;
        const size_t idx = (size_t)(row0+r)*HD + col;
        float pre = tanhf_fast(acc[i2][q] + bias_tab[codes_s[r]*HD + col]);
        float zv = zF_in[idx];
        float m = (1.f - zv)*sumhF[idx] + zv*pre;
        hF[idx] = m;
        hB[idx] = (short)f2bf(m);
      }
    }
  } else {
    float p[4];
    #pragma unroll
    for (int q=0;q<4;++q) p[q]=0.f;
    #pragma unroll
    for (int i2=0;i2<2;++i2){
      const int col = cg*128 + (ntp*2+i2)*16 + lm;
      float wv = w_topo[col];
      float bnl = bias_tab[col];
      #pragma unroll
      for (int q=0;q<4;++q){
        float hid = fmaxf(acc[i2][q] + bnl, 0.f);
        p[q] = fmaf(hid, wv, p[q]);
      }
    }
    #pragma unroll
    for (int s=1;s<16;s<<=1)
      #pragma unroll
      for (int q=0;q<4;++q) p[q] += __shfl_xor(p[q], s);
    if (lm==0){
      #pragma unroll
      for (int q=0;q<4;++q)
        topo_p[(size_t)(cg*4+ntp)*NROWS + row0 + mt*16 + g*4 + q] = p[q];
    }
  }
}

// r gate: [16384,512] x Ur^T with in-register k-reduction -> sum_gated bf16.
// grid (128 row-tiles x 4 cg), 128 h_nei rows (16 nodes) x 128 cols per block.
__global__ __launch_bounds__(512) void ggru_r_k(
    const short* __restrict__ fUr,
    const short* __restrict__ hnB,
    const int* __restrict__ hpn_idx,
    const float* __restrict__ wxbr_mp,
    short* __restrict__ sgB)
{
  __shared__ __align__(16) short stage[16][4096];
  __shared__ int codes_s[16];
  const int tt = threadIdx.x, l = tt&63, w = tt>>6, lm = l&15, g = l>>4;
  const int row0 = blockIdx.x*128, cg = blockIdx.y;
  if (tt<16) codes_s[tt] = hpn_idx[(row0>>3) + tt];
  const short* gsrc = fUr + ((size_t)(cg*8 + w)*16)*512 + (size_t)l*8;
  #pragma unroll
  for (int kc=0;kc<8;++kc) dma16(gsrc + (size_t)kc*512, &stage[kc][w*512 + l*8]);
  s8b af[16];
  {
    const s8b* arow = (const s8b*)(hnB + (size_t)(row0 + w*16 + lm)*HD);
    #pragma unroll
    for (int kc=0;kc<16;++kc) af[kc] = arow[kc*4 + g];
  }
  asm volatile("s_waitcnt vmcnt(0)" ::: "memory");
  __syncthreads();
  #pragma unroll
  for (int kc=8;kc<16;++kc) dma16(gsrc + (size_t)kc*512, &stage[kc][w*512 + l*8]);
  f4 acc[8];
  #pragma unroll
  for (int i=0;i<8;++i) acc[i]=f4zero();
  #pragma unroll
  for (int kc=0;kc<8;++kc){
    #pragma unroll
    for (int ot=0;ot<8;++ot){
      s8b b = ((const s8b*)&stage[kc][ot*512])[l];
      acc[ot] = MFMA16(af[kc], b, acc[ot]);
    }
  }
  asm volatile("s_waitcnt vmcnt(0)" ::: "memory");
  __syncthreads();
  #pragma unroll
  for (int kc=8;kc<16;++kc){
    #pragma unroll
    for (int ot=0;ot<8;++ot){
      s8b b = ((const s8b*)&stage[kc][ot*512])[l];
      acc[ot] = MFMA16(af[kc], b, acc[ot]);
    }
  }
  // epilogue: r = sig(acc + bias); gate with bf16 h_nei; reduce k=8 in regs
  const int nloc = w*2 + (g>>1);            // local node for this lane's rows
  const int code = codes_s[nloc];
  #pragma unroll
  for (int ot=0;ot<8;++ot){
    const int col = cg*128 + ot*16 + lm;
    float part = 0.f;
    #pragma unroll
    for (int q=0;q<4;++q){
      const int lr = w*16 + g*4 + q;
      float rv = sigf(acc[ot][q] + wxbr_mp[code*HD + col]);
      part += rv * bf2f((unsigned short)hnB[(size_t)(row0+lr)*HD + col]);
    }
    part += __shfl_xor(part, 16);           // combine g with g^1 (same node)
    if ((g&1)==0){
      const int node = (row0>>3) + nloc;
      sgB[(size_t)node*HD + col] = (short)f2bf(part);
    }
  }
}

// ---------------- scan step kernel A: z, r, nuc GEMMs on h(t) ----------------
// grid (16 row-tiles x 12 cg), 128 rows x 128 cols, single round on chip.
__global__ __launch_bounds__(512) void zrnuc_k(
    int t, const int* __restrict__ nuc_idx,
    const short* __restrict__ fz, const short* __restrict__ fr, const short* __restrict__ fnuc,
    const short* __restrict__ hB, const float* __restrict__ hF,
    const float* __restrict__ wxbz, const float* __restrict__ wxbr,
    const float* __restrict__ latp, const float* __restrict__ w_nuc,
    float* __restrict__ zF, short* __restrict__ ghB, float* __restrict__ nucp)
{
  const int cg = blockIdx.y;
  const int mat = cg>>2;
  if (t==0 && mat==2) return;
  __shared__ __align__(16) short stage[16][4096];
  __shared__ int codes_s[128];
  const int tt = threadIdx.x, l = tt&63, w = tt>>6, lm = l&15, g = l>>4;
  const int row0 = blockIdx.x*128;
  const short* frag = (mat==0)?fz:((mat==1)?fr:fnuc);
  const int otb = (cg&3)*8;
  if (tt<128) codes_s[tt] = nuc_idx[(size_t)(row0+tt)*LSEQ + t];
  const short* gsrc = frag + ((size_t)(otb + w)*16)*512 + (size_t)l*8;
  #pragma unroll
  for (int kc=0;kc<8;++kc) dma16(gsrc + (size_t)kc*512, &stage[kc][w*512 + l*8]);
  s8b af[16];
  {
    const s8b* hrow = (const s8b*)(hB + (size_t)(row0 + w*16 + lm)*HD);
    #pragma unroll
    for (int kc=0;kc<16;++kc) af[kc] = hrow[kc*4 + g];
  }
  asm volatile("s_waitcnt vmcnt(0)" ::: "memory");
  __syncthreads();
  #pragma unroll
  for (int kc=8;kc<16;++kc) dma16(gsrc + (size_t)kc*512, &stage[kc][w*512 + l*8]);
  f4 acc[8];
  #pragma unroll
  for (int i=0;i<8;++i) acc[i]=f4zero();
  #pragma unroll
  for (int kc=0;kc<8;++kc){
    #pragma unroll
    for (int ot=0;ot<8;++ot){
      s8b b = ((const s8b*)&stage[kc][ot*512])[l];
      acc[ot] = MFMA16(af[kc], b, acc[ot]);
    }
  }
  asm volatile("s_waitcnt vmcnt(0)" ::: "memory");
  __syncthreads();
  #pragma unroll
  for (int kc=8;kc<16;++kc){
    #pragma unroll
    for (int ot=0;ot<8;++ot){
      s8b b = ((const s8b*)&stage[kc][ot*512])[l];
      acc[ot] = MFMA16(af[kc], b, acc[ot]);
    }
  }
  const int colb = (cg&3)*128;
  if (mat==0){
    #pragma unroll
    for (int ot=0;ot<8;++ot){
      const int col = colb + ot*16 + lm;
      #pragma unroll
      for (int q=0;q<4;++q){
        const int r = w*16 + g*4 + q;
        zF[(size_t)(row0+r)*HD + col] = sigf(acc[ot][q] + wxbz[codes_s[r]*HD + col]);
      }
    }
  } else if (mat==1){
    #pragma unroll
    for (int ot=0;ot<8;++ot){
      const int col = colb + ot*16 + lm;
      #pragma unroll
      for (int q=0;q<4;++q){
        const int r = w*16 + g*4 + q;
        float rv = sigf(acc[ot][q] + wxbr[codes_s[r]*HD + col]);
        ghB[(size_t)(row0+r)*HD + col] = (short)f2bf(rv * hF[(size_t)(row0+r)*HD + col]);
      }
    }
  } else {
    float p[4][NNUC];
    #pragma unroll
    for (int q=0;q<4;++q)
      #pragma unroll
      for (int j=0;j<NNUC;++j) p[q][j]=0.f;
    #pragma unroll
    for (int ot=0;ot<8;++ot){
      const int col = colb + ot*16 + lm;
      #pragma unroll
      for (int q=0;q<4;++q){
        const int r = w*16 + g*4 + q;
        float hid = fmaxf(acc[ot][q] + latp[(size_t)(row0+r)*HD + col], 0.f);
        #pragma unroll
        for (int j=0;j<NNUC;++j) p[q][j] = fmaf(hid, w_nuc[(size_t)j*HD + col], p[q][j]);
      }
    }
    #pragma unroll
    for (int s=1;s<16;s<<=1)
      #pragma unroll
      for (int q=0;q<4;++q)
        #pragma unroll
        for (int j=0;j<NNUC;++j) p[q][j] += __shfl_xor(p[q][j], s);
    if (lm==0){
      const int slab = cg&3;
      #pragma unroll
      for (int q=0;q<4;++q){
        const int row = row0 + w*16 + g*4 + q;
        #pragma unroll
        for (int j=0;j<NNUC;++j)
          nucp[((size_t)slab*NROWS + row)*NNUC + j] = p[q][j];
      }
    }
  }
}

// ---------------- scan step kernel B: candidate GEMM + h update ----------------
// grid (32 row-tiles x 4 cg), 64 rows x 128 cols, single round on chip.
__global__ __launch_bounds__(512) void cand_k(
    int t, const int* __restrict__ nuc_idx,
    const short* __restrict__ fh,
    const short* __restrict__ ghB,
    const float* __restrict__ wxbh,
    const float* __restrict__ zF, float* __restrict__ hF, short* __restrict__ hB,
    const float* __restrict__ nucp, const float* __restrict__ b_nuc,
    float* __restrict__ out_nuc)
{
  __shared__ __align__(16) short stage[16][4096];
  __shared__ int codes_s[64];
  const int tt = threadIdx.x, l = tt&63, w = tt>>6, lm = l&15, g = l>>4;
  const int row0 = blockIdx.x*64, cg = blockIdx.y;
  if (tt<64) codes_s[tt] = nuc_idx[(size_t)(row0+tt)*LSEQ + t];
  const int mt = w>>1, oth = w&1;
  const short* gsrc = fh + ((size_t)(cg*8 + w)*16)*512 + (size_t)l*8;
  #pragma unroll
  for (int kc=0;kc<8;++kc) dma16(gsrc + (size_t)kc*512, &stage[kc][w*512 + l*8]);
  s8b af[16];
  {
    const s8b* grow = (const s8b*)(ghB + (size_t)(row0 + mt*16 + lm)*HD);
    #pragma unroll
    for (int kc=0;kc<16;++kc) af[kc] = grow[kc*4 + g];
  }
  asm volatile("s_waitcnt vmcnt(0)" ::: "memory");
  __syncthreads();
  #pragma unroll
  for (int kc=8;kc<16;++kc) dma16(gsrc + (size_t)kc*512, &stage[kc][w*512 + l*8]);
  f4 acc[4];
  #pragma unroll
  for (int i=0;i<4;++i) acc[i]=f4zero();
  #pragma unroll
  for (int kc=0;kc<8;++kc){
    #pragma unroll
    for (int i=0;i<4;++i){
      s8b b = ((const s8b*)&stage[kc][(oth*4+i)*512])[l];
      acc[i] = MFMA16(af[kc], b, acc[i]);
    }
  }
  asm volatile("s_waitcnt vmcnt(0)" ::: "memory");
  __syncthreads();
  #pragma unroll
  for (int kc=8;kc<16;++kc){
    #pragma unroll
    for (int i=0;i<4;++i){
      s8b b = ((const s8b*)&stage[kc][(oth*4+i)*512])[l];
      acc[i] = MFMA16(af[kc], b, acc[i]);
    }
  }
  #pragma unroll
  for (int i=0;i<4;++i){
    const int col = cg*128 + (oth*4+i)*16 + lm;
    #pragma unroll
    for (int q=0;q<4;++q){
      const int r = mt*16 + g*4 + q;
      const size_t idx = (size_t)(row0+r)*HD + col;
      float pre = tanhf_fast(acc[i][q] + wxbh[codes_s[r]*HD + col]);
      float zv = zF[idx];
      float hn = (1.f - zv)*hF[idx] + zv*pre;
      hF[idx] = hn;
      hB[idx] = (short)f2bf(hn);
    }
  }
  // reduce nuc partials for l = t-1 (written by zrnuc_k(t))
  if (t > 0 && cg == 0 && tt < 64*NNUC){
    int rr = tt/NNUC, j = tt - rr*NNUC;
    int row = row0 + rr;
    float s2 = b_nuc[j];
    #pragma unroll
    for (int s4=0;s4<4;++s4) s2 += nucp[((size_t)s4*NROWS + row)*NNUC + j];
    out_nuc[((size_t)row*LSEQ + (t-1))*NNUC + j] = s2;
  }
}

// ---------------- tail heads: nuc(l=63) + hpn on h(64) ----------------
__global__ __launch_bounds__(512) void heads_k(
    const short* __restrict__ fnuc, const short* __restrict__ fhpn,
    const short* __restrict__ hB,
    const float* __restrict__ latp, const float* __restrict__ w_nuc,
    const float* __restrict__ b_hpn_nl, const float* __restrict__ w_hpn,
    float* __restrict__ nucpH, float* __restrict__ hpnp)
{
  __shared__ __align__(16) short stage[16][4096];
  const int tt = threadIdx.x, l = tt&63, w = tt>>6, lm = l&15, g = l>>4;
  const int rt = blockIdx.x, row0 = rt*32, cg = blockIdx.y;
  const int mat = cg>>2;
  const short* frag = mat ? fhpn : fnuc;
  const int mt = w>>2, ntp = w&3;
  const short* gsrc = frag + ((size_t)((cg&3)*8 + w)*16)*512 + (size_t)l*8;
  #pragma unroll
  for (int kc=0;kc<8;++kc) dma16(gsrc + (size_t)kc*512, &stage[kc][w*512 + l*8]);
  s8b af[16];
  {
    const s8b* hrow = (const s8b*)(hB + (size_t)(row0 + mt*16 + lm)*HD);
    #pragma unroll
    for (int kc=0;kc<16;++kc) af[kc] = hrow[kc*4 + g];
  }
  asm volatile("s_waitcnt vmcnt(0)" ::: "memory");
  __syncthreads();
  #pragma unroll
  for (int kc=8;kc<16;++kc) dma16(gsrc + (size_t)kc*512, &stage[kc][w*512 + l*8]);
  f4 acc[2]; acc[0]=f4zero(); acc[1]=f4zero();
  #pragma unroll
  for (int kc=0;kc<8;++kc){
    #pragma unroll
    for (int i2=0;i2<2;++i2){
      s8b b = ((const s8b*)&stage[kc][(ntp*2+i2)*512])[l];
      acc[i2] = MFMA16(af[kc], b, acc[i2]);
    }
  }
  asm volatile("s_waitcnt vmcnt(0)" ::: "memory");
  __syncthreads();
  #pragma unroll
  for (int kc=8;kc<16;++kc){
    #pragma unroll
    for (int i2=0;i2<2;++i2){
      s8b b = ((const s8b*)&stage[kc][(ntp*2+i2)*512])[l];
      acc[i2] = MFMA16(af[kc], b, acc[i2]);
    }
  }
  const int slab = (cg&3)*4 + ntp;
  if (mat==0){
    float p[4][NNUC];
    #pragma unroll
    for (int q=0;q<4;++q)
      #pragma unroll
      for (int j=0;j<NNUC;++j) p[q][j]=0.f;
    #pragma unroll
    for (int i2=0;i2<2;++i2){
      const int col = (cg&3)*128 + (ntp*2+i2)*16 + lm;
      #pragma unroll
      for (int q=0;q<4;++q){
        const int r = mt*16 + g*4 + q;
        float hid = fmaxf(acc[i2][q] + latp[(size_t)(row0+r)*HD + col], 0.f);
        #pragma unroll
        for (int j=0;j<NNUC;++j) p[q][j] = fmaf(hid, w_nuc[(size_t)j*HD + col], p[q][j]);
      }
    }
    #pragma unroll
    for (int s=1;s<16;s<<=1)
      #pragma unroll
      for (int q=0;q<4;++q)
        #pragma unroll
        for (int j=0;j<NNUC;++j) p[q][j] += __shfl_xor(p[q][j], s);
    if (lm==0){
      #pragma unroll
      for (int q=0;q<4;++q){
        const int row = row0 + mt*16 + g*4 + q;
        #pragma unroll
        for (int j=0;j<NNUC;++j)
          nucpH[((size_t)slab*NROWS + row)*NNUC + j] = p[q][j];
      }
    }
  } else {
    float p[4][NHPN];
    #pragma unroll
    for (int q=0;q<4;++q)
      #pragma unroll
      for (int j=0;j<NHPN;++j) p[q][j]=0.f;
    #pragma unroll
    for (int i2=0;i2<2;++i2){
      const int col = (cg&3)*128 + (ntp*2+i2)*16 + lm;
      float bnl = b_hpn_nl[col];
      #pragma unroll
      for (int q=0;q<4;++q){
        float hid = fmaxf(acc[i2][q] + bnl, 0.f);
        #pragma unroll
        for (int j=0;j<NHPN;++j) p[q][j] = fmaf(hid, w_hpn[(size_t)j*HD + col], p[q][j]);
      }
    }
    #pragma unroll
    for (int s=1;s<16;s<<=1)
      #pragma unroll
      for (int q=0;q<4;++q)
        #pragma unroll
        for (int j=0;j<NHPN;++j) p[q][j] += __shfl_xor(p[q][j], s);
    if (lm==0){
      #pragma unroll
      for (int q=0;q<4;++q){
        const int row = row0 + mt*16 + g*4 + q;
        #pragma unroll
        for (int j=0;j<NHPN;++j)
          hpnp[((size_t)slab*NROWS + row)*NHPN + j] = p[q][j];
      }
    }
  }
}

__global__ void final_red_k(const float* __restrict__ nucpH, const float* __restrict__ hpnp,
    const float* __restrict__ topo_p,
    const float* __restrict__ b_nuc, const float* __restrict__ b_hpn, const float* __restrict__ b_topo,
    const float* __restrict__ hF,
    float* __restrict__ out_newh, float* __restrict__ out_hpn, float* __restrict__ out_nuc,
    float* __restrict__ out_stop)
{
  int gid = blockIdx.x*256 + threadIdx.x;   // grid 128x256 = 32768
  if (gid < NROWS*NNUC){
    int n = gid/NNUC, j = gid - n*NNUC;
    float s = b_nuc[j];
    #pragma unroll
    for (int s8=0;s8<16;++s8) s += nucpH[((size_t)s8*NROWS + n)*NNUC + j];
    out_nuc[((size_t)n*LSEQ + 63)*NNUC + j] = s;
  } else if (gid < NROWS*NNUC + NROWS*NHPN){
    int g2 = gid - NROWS*NNUC;
    int n = g2/NHPN, j = g2 - n*NHPN;
    float s = b_hpn[j];
    #pragma unroll
    for (int s8=0;s8<16;++s8) s += hpnp[((size_t)s8*NROWS + n)*NHPN + j];
    out_hpn[(size_t)n*NHPN + j] = s;
  } else if (gid < NROWS*NNUC + NROWS*NHPN + NROWS){
    int n = gid - (NROWS*NNUC + NROWS*NHPN);
    float s = b_topo[0];
    #pragma unroll
    for (int s16=0;s16<16;++s16) s += topo_p[(size_t)s16*NROWS + n];
    out_stop[n] = s;
  }
  const float4* src = (const float4*)hF;
  float4* dst = (float4*)out_newh;
  for (int i = gid; i < NROWS*HD/4; i += 32768) dst[i] = src[i];
}

// ---------------- host ----------------
extern "C" void kernel_launch(void* const* d_in, const int* in_sizes, int n_in,
                              void* d_out, int out_size, void* d_ws, size_t ws_size,
                              hipStream_t stream_){
  (void)in_sizes; (void)n_in; (void)out_size; (void)ws_size;
  const int*   hpn_idx      = (const int*)d_in[0];
  const int*   nuc_idx      = (const int*)d_in[1];
  const float* h_nei        = (const float*)d_in[2];
  const float* graph_latent = (const float*)d_in[3];
  const float* Wz_mp=(const float*)d_in[4];  const float* bz_mp=(const float*)d_in[5];
  const float* Wr_mp=(const float*)d_in[6];  const float* br_mp=(const float*)d_in[7];
  const float* Ur_mp=(const float*)d_in[8];
  const float* Wh_mp=(const float*)d_in[9];  const float* bh_mp=(const float*)d_in[10];
  const float* Wz_nuc=(const float*)d_in[11]; const float* bz_nuc=(const float*)d_in[12];
  const float* Wr_nuc=(const float*)d_in[13]; const float* br_nuc=(const float*)d_in[14];
  const float* Wh_nuc=(const float*)d_in[15]; const float* bh_nuc=(const float*)d_in[16];
  const float* W_hpn_nl=(const float*)d_in[17]; const float* b_hpn_nl=(const float*)d_in[18];
  const float* W_hpn=(const float*)d_in[19];  const float* b_hpn=(const float*)d_in[20];
  const float* W_nuc_nl=(const float*)d_in[21]; const float* b_nuc_nl=(const float*)d_in[22];
  const float* W_nuc=(const float*)d_in[23];  const float* b_nuc=(const float*)d_in[24];
  const float* W_topo_nl=(const float*)d_in[25]; const float* b_topo_nl=(const float*)d_in[26];
  const float* W_topo=(const float*)d_in[27]; const float* b_topo=(const float*)d_in[28];

  float* ws = (float*)d_ws;
  size_t off = 0;
  auto take = [&](size_t nfl){ float* p = ws + off; off += nfl; return p; };
  float* wt_nl_lat = take((size_t)LATD*HD);
  // scan bf16 fragment weights
  short* fz    = (short*)take((size_t)HD*HD/2);
  short* fr    = (short*)take((size_t)HD*HD/2);
  short* fh    = (short*)take((size_t)HD*HD/2);
  short* fnuc  = (short*)take((size_t)HD*HD/2);
  short* fhpn  = (short*)take((size_t)HD*HD/2);
  // graphgru bf16 fragment weights
  short* fWzh  = (short*)take((size_t)HD*HD/2);
  short* fUr   = (short*)take((size_t)HD*HD/2);
  short* fWhh  = (short*)take((size_t)HD*HD/2);
  short* fWtopo= (short*)take((size_t)HD*HD/2);
  float* wxbz = take((size_t)NNUC*HD);
  float* wxbr = take((size_t)NNUC*HD);
  float* wxbh = take((size_t)NNUC*HD);
  float* wxbz_mp = take((size_t)NHPN*HD);
  float* wxbr_mp = take((size_t)NHPN*HD);
  float* wxbh_mp = take((size_t)NHPN*HD);
  float* latp = take((size_t)NROWS*HD);
  float* hF   = take((size_t)NROWS*HD);
  short* hB   = (short*)take((size_t)NROWS*HD/2);
  short* ghB  = (short*)take((size_t)NROWS*HD/2);
  float* zF   = take((size_t)NROWS*HD);
  float* sumhF = take((size_t)NROWS*HD);
  short* sumhB = (short*)take((size_t)NROWS*HD/2);
  short* sgB   = (short*)take((size_t)NROWS*HD/2);
  short* hnB   = (short*)take((size_t)NROWS*KNEI*HD/2);
  float* nucp = take((size_t)4*NROWS*NNUC);
  float* nucpH= take((size_t)16*NROWS*NNUC);
  float* hpnp = take((size_t)16*NROWS*NHPN);
  float* topo_p = take((size_t)16*NROWS);

  float* out       = (float*)d_out;
  float* out_newh  = out;
  float* out_hpn   = out + (size_t)NROWS*HD;
  float* out_nuc   = out_hpn + (size_t)NROWS*NHPN;
  float* out_stop  = out_nuc + (size_t)NROWS*LSEQ*NNUC;

  transpose_w<<<(LATD*HD+255)/256, 256, 0, stream_>>>(W_nuc_nl, wt_nl_lat, HD+LATD, HD, LATD);

  const int FB = (HD*HD+255)/256;
  fragprep_k<<<FB,256,0,stream_>>>(Wz_nuc,   fz,    HD+NNUC, NNUC);
  fragprep_k<<<FB,256,0,stream_>>>(Wr_nuc,   fr,    HD+NNUC, NNUC);
  fragprep_k<<<FB,256,0,stream_>>>(Wh_nuc,   fh,    HD+NNUC, NNUC);
  fragprep_k<<<FB,256,0,stream_>>>(W_nuc_nl, fnuc,  HD+LATD, 0);
  fragprep_k<<<FB,256,0,stream_>>>(W_hpn_nl, fhpn,  HD,      0);
  fragprep_k<<<FB,256,0,stream_>>>(Wz_mp,    fWzh,  HD+NHPN, NHPN);
  fragprep_k<<<FB,256,0,stream_>>>(Ur_mp,    fUr,   HD,      0);
  fragprep_k<<<FB,256,0,stream_>>>(Wh_mp,    fWhh,  HD+NHPN, NHPN);
  fragprep_k<<<FB,256,0,stream_>>>(W_topo_nl,fWtopo,HD,      0);

  const int WB = (NNUC*HD+255)/256;
  wxbprep2_k<<<WB,256,0,stream_>>>(Wz_nuc, bz_nuc, wxbz, HD+NNUC, NNUC);
  wxbprep2_k<<<WB,256,0,stream_>>>(Wr_nuc, br_nuc, wxbr, HD+NNUC, NNUC);
  wxbprep2_k<<<WB,256,0,stream_>>>(Wh_nuc, bh_nuc, wxbh, HD+NNUC, NNUC);
  const int WB2 = (NHPN*HD+255)/256;
  wxbprep2_k<<<WB2,256,0,stream_>>>(Wz_mp, bz_mp, wxbz_mp, HD+NHPN, NHPN);
  wxbprep2_k<<<WB2,256,0,stream_>>>(Wr_mp, br_mp, wxbr_mp, NHPN,    NHPN);
  wxbprep2_k<<<WB2,256,0,stream_>>>(Wh_mp, bh_mp, wxbh_mp, HD+NHPN, NHPN);

  latp_k<<<NROWS/16, 512, 0, stream_>>>(graph_latent, wt_nl_lat, b_nuc_nl, latp);

  // ---- GraphGRU via MFMA ----
  sumcast_k<<<512, 512, 0, stream_>>>(h_nei, sumhF, sumhB, hnB);
  ggru_gemm_k<<<dim3(64,4), 512, 0, stream_>>>(
      0, fWzh, sumhB, hpn_idx, wxbz_mp, nullptr, nullptr, nullptr,
      zF, nullptr, nullptr, nullptr);
  ggru_r_k<<<dim3(128,4), 512, 0, stream_>>>(fUr, hnB, hpn_idx, wxbr_mp, sgB);
  ggru_gemm_k<<<dim3(64,4), 512, 0, stream_>>>(
      1, fWhh, sgB, hpn_idx, wxbh_mp, sumhF, zF, nullptr,
      nullptr, hF, hB, nullptr);
  ggru_gemm_k<<<dim3(64,4), 512, 0, stream_>>>(
      2, fWtopo, hB, hpn_idx, b_topo_nl, nullptr, nullptr, W_topo,
      nullptr, nullptr, nullptr, topo_p);

  // ---- scan ----
  for (int t = 0; t < LSEQ; ++t){
    zrnuc_k<<<dim3(16,12), 512, 0, stream_>>>(
        t, nuc_idx, fz, fr, fnuc, hB, hF,
        wxbz, wxbr, latp, W_nuc, zF, ghB, nucp);
    cand_k<<<dim3(32,4), 512, 0, stream_>>>(
        t, nuc_idx, fh, ghB, wxbh, zF, hF, hB,
        nucp, b_nuc, out_nuc);
  }

  heads_k<<<dim3(64,8), 512, 0, stream_>>>(
      fnuc, fhpn, hB, latp, W_nuc, b_hpn_nl, W_hpn, nucpH, hpnp);
  final_red_k<<<128, 256, 0, stream_>>>(
      nucpH, hpnp, topo_p, b_nuc, b_hpn, b_topo, hF,
      out_newh, out_hpn, out_nuc, out_stop);
}